// Round 13
// baseline (483.153 us; speedup 1.0000x reference)
//
#include <hip/hip_runtime.h>

typedef short s16x8 __attribute__((ext_vector_type(8)));
typedef float f32x4 __attribute__((ext_vector_type(4)));
typedef float f32x16 __attribute__((ext_vector_type(16)));
typedef unsigned short u16x4 __attribute__((ext_vector_type(4)));
typedef unsigned int u32x4 __attribute__((ext_vector_type(4)));

#define QSCALE (0.08838834764831845f * 1.4426950408889634f)

__device__ __forceinline__ unsigned short f2bf(float f) {
  unsigned int u = __float_as_uint(f);
  u += 0x7fffu + ((u >> 16) & 1u);
  return (unsigned short)(u >> 16);
}
__device__ __forceinline__ float bf2f(unsigned short h) {
  return __uint_as_float((unsigned int)h << 16);
}
__device__ __forceinline__ float fast_exp2(float x) {
  float r;
  asm("v_exp_f32 %0, %1" : "=v"(r) : "v"(x));
  return r;
}

__device__ __forceinline__ void gload16(const void* gp, void* lp) {
  __builtin_amdgcn_global_load_lds(
      (const __attribute__((address_space(1))) void*)gp,
      (__attribute__((address_space(3))) void*)lp,
      16, 0, 0);
}

// ---------------- cast f32 -> bf16, 4 at a time ----------------
__global__ void cast_f32_bf16_x4(const float* __restrict__ in,
                                 unsigned short* __restrict__ out, int n4) {
  int i = blockIdx.x * 256 + threadIdx.x;
  if (i >= n4) return;
  f32x4 v = *((const f32x4*)in + i);
  u16x4 o;
  o[0] = f2bf(v[0]); o[1] = f2bf(v[1]); o[2] = f2bf(v[2]); o[3] = f2bf(v[3]);
  *((u16x4*)out + i) = o;
}

// ---------------- compact G2c[h*128+m][d] = (1/QSCALE) * sum_j g_kv[h][d][j]*Wlin[m][j] ----
__global__ void g2fill_kernel(const float* __restrict__ g_kv,
                              const float* __restrict__ Wlin,
                              unsigned short* __restrict__ G2c) {
  int h = blockIdx.x, m = blockIdx.y, d = threadIdx.x;
  const float* gk = g_kv + ((size_t)h * 128 + d) * 128;
  const float* wl = Wlin + (size_t)m * 128;
  float s = 0.f;
  for (int j = 0; j < 128; ++j) s += gk[j] * wl[j];
  G2c[((size_t)h * 128 + m) * 128 + d] = f2bf(s * (1.0f / QSCALE));
}

// ============ 256x256 8-phase GEMM (m201 template): C=A@B^T + bias, bf16 out ============
// 512 thr = 8 waves (2Mx4N), BK=64, LDS 128KB (2 K-tile bufs x {A,B} x 2 halves),
// st_16x32 swizzle via linear-dest gload_lds + pre-swizzled source + swizzled ds_read.
// Requires: lda=ldb=K, N multiple of 256, K multiple of 128.
__global__ __launch_bounds__(512, 1) void gemm256_bt(
    const unsigned short* __restrict__ A, const unsigned short* __restrict__ B,
    const float* __restrict__ bias, unsigned short* __restrict__ C,
    int M, int N, int K) {
  __shared__ __align__(16) unsigned short lds[2 * 2 * 2 * 128 * 64];  // 128 KB, 8 x 16KB regions
  const int tid = threadIdx.x;
  const int lane = tid & 63;
  const int wid = tid >> 6;
  const int wr = wid >> 2, wc = wid & 3;  // 2 x 4 wave grid
  const int mt = blockIdx.x, nt = blockIdx.y;

  f32x4 acc[8][4] = {};

  // staging geometry: chunk c = rep*512+tid, linear dest byte D=c*16,
  // source logical byte L = D ^ ((D>>9&1)<<5)  (st_16x32, 16B-block-preserving)
  int st_row[2], st_col[2];
#pragma unroll
  for (int rep = 0; rep < 2; ++rep) {
    int D = (rep * 512 + tid) * 16;
    int L = D ^ (((D >> 9) & 1) << 5);
    st_row[rep] = L >> 7;          // row in 128-row half
    st_col[rep] = (L & 127) >> 1;  // bf16 col in BK=64
  }
  const int NT = K / 64;

#define G256_STAGE(mat, buf, half, kt)                                           \
  {                                                                              \
    const unsigned short* src_ = (mat) ? B : A;                                  \
    int base_ = ((mat) ? nt : mt) * 256;                                         \
    int lim_ = ((mat) ? N : M) - 1;                                              \
    _Pragma("unroll") for (int rep = 0; rep < 2; ++rep) {                        \
      int grow = base_ + (half) * 128 + st_row[rep];                             \
      if (grow > lim_) grow = lim_;                                              \
      gload16(src_ + (size_t)grow * K + (kt) * 64 + st_col[rep],                 \
              (char*)lds + (((mat) * 2 + (buf)) * 2 + (half)) * 16384 +          \
                  (rep * 512 + tid) * 16);                                       \
    }                                                                            \
  }

  // prologue: tile 0 -> buf 0
  G256_STAGE(0, 0, 0, 0);
  G256_STAGE(0, 0, 1, 0);
  G256_STAGE(1, 0, 0, 0);
  G256_STAGE(1, 0, 1, 0);
  asm volatile("s_waitcnt vmcnt(0)" ::: "memory");
  __builtin_amdgcn_sched_barrier(0);
  __builtin_amdgcn_s_barrier();

  const int swzkey = ((lane >> 2) & 1) << 5;  // read-side st_16x32 key (row bit2 = lane bit2)
  const int aRowB = lane & 15;
  const int b0base = (lane >> 4) << 4;

  s16x8 areg[4][2], breg[4][2];
  const int NI = NT / 2;

  for (int i = 0; i < NI; ++i) {
#pragma unroll
    for (int q = 0; q < 8; ++q) {
      const int half_it = q >> 2;  // 0: tile 2i, 1: tile 2i+1
      const int buf = half_it;     // tile t lives in buf t&1 (2i even)
      const int mh = (q >> 1) & 1, nh = q & 1;
      // ---- ds-read register quadrant (A reloaded when nh==0; B fn-pair when mh==0)
      if (nh == 0) {
#pragma unroll
        for (int mm = 0; mm < 4; ++mm) {
          int rowInHalf = (mh * 4 + mm) * 16 + aRowB;
          const char* abase =
              (const char*)lds + ((0 * 2 + buf) * 2 + wr) * 16384 + rowInHalf * 128;
#pragma unroll
          for (int kk = 0; kk < 2; ++kk)
            areg[mm][kk] = *(const s16x8*)(abase + ((kk * 64 + b0base) ^ swzkey));
        }
      }
      if (mh == 0) {
#pragma unroll
        for (int nn = 0; nn < 2; ++nn) {
          int fn = nh * 2 + nn;
          int rowInHalf = (wc & 1) * 64 + fn * 16 + aRowB;
          const char* bbase =
              (const char*)lds + ((1 * 2 + buf) * 2 + (wc >> 1)) * 16384 + rowInHalf * 128;
#pragma unroll
          for (int kk = 0; kk < 2; ++kk)
            breg[fn][kk] = *(const s16x8*)(bbase + ((kk * 64 + b0base) ^ swzkey));
        }
      }
      // ---- stage one half-tile of the next-needed K-tile (A halves first: longer lead)
      {
        int tst = 2 * i + 1 + half_it;
        if (tst < NT) {
          int smat = (q & 3) >> 1;
          int shalf = q & 1;
          int sbuf = 1 - half_it;
          G256_STAGE(smat, sbuf, shalf, tst);
        }
      }
      __builtin_amdgcn_s_barrier();
      asm volatile("s_waitcnt lgkmcnt(0)" ::: "memory");
      __builtin_amdgcn_sched_barrier(0);
      __builtin_amdgcn_s_setprio(1);
#pragma unroll
      for (int mm = 0; mm < 4; ++mm)
#pragma unroll
        for (int nn = 0; nn < 2; ++nn) {
          const int fm = mh * 4 + mm, fn = nh * 2 + nn;
          acc[fm][fn] = __builtin_amdgcn_mfma_f32_16x16x32_bf16(
              areg[mm][0], breg[fn][0], acc[fm][fn], 0, 0, 0);
          acc[fm][fn] = __builtin_amdgcn_mfma_f32_16x16x32_bf16(
              areg[mm][1], breg[fn][1], acc[fm][fn], 0, 0, 0);
        }
      __builtin_amdgcn_s_setprio(0);
      if ((q & 3) == 3) {
        asm volatile("s_waitcnt vmcnt(0)" ::: "memory");
      }
      __builtin_amdgcn_sched_barrier(0);
      __builtin_amdgcn_s_barrier();
    }
  }
  // epilogue
#pragma unroll
  for (int fm = 0; fm < 8; ++fm) {
#pragma unroll
    for (int fn = 0; fn < 4; ++fn) {
#pragma unroll
      for (int rg = 0; rg < 4; ++rg) {
        int rr = mt * 256 + wr * 128 + fm * 16 + ((lane >> 4) << 2) + rg;
        int cc = nt * 256 + wc * 64 + fn * 16 + (lane & 15);
        if (rr < M) C[(size_t)rr * N + cc] = f2bf(acc[fm][fn][rg] + bias[cc]);
      }
    }
  }
#undef G256_STAGE
}

// ---------------- GEMM: C[M,N] = A[M,K] @ B[N,K]^T (+ epilogue) ----------------
// MODE 1: f32 out, +bias[cc]
// MODE 3: block-diag per-head (A col offset nt*128, compact B), nsplit-way merge epilogue
template <int MODE>
__global__ __launch_bounds__(256) void gemm_bt(
    const unsigned short* __restrict__ A, const unsigned short* __restrict__ B,
    const float* __restrict__ bias, void* __restrict__ Cout,
    int M, int N, int K, int lda, int ldb,
    const float* __restrict__ o0buf, const float* __restrict__ zbuf,
    const float* __restrict__ o1buf, const float* __restrict__ lbuf, int nsplit) {
  __shared__ __align__(16) unsigned short Asm_[128 * 64];
  __shared__ __align__(16) unsigned short Bsm_[128 * 64];
  const int tid = threadIdx.x;
  const int wid = tid >> 6, lane = tid & 63;
  const int mt = blockIdx.x, nt = blockIdx.y;
  const int wr = wid >> 1, wc = wid & 1;
  const int acol = (MODE == 3) ? nt * 128 : 0;
  f32x4 acc[4][4] = {};

  const int st_srccol = ((((lane & 7) << 4) ^ ((lane >> 3) << 4)) >> 1);  // elements
  const int st_rowoff = (lane >> 3);

  for (int k0 = 0; k0 < K; k0 += 64) {
    __syncthreads();
#pragma unroll
    for (int r = 0; r < 4; ++r) {
      int c = wid * 4 + r;
      int lrow = c * 8 + st_rowoff;
      int arow = mt * 128 + lrow; if (arow > M - 1) arow = M - 1;
      gload16(A + (size_t)arow * lda + acol + k0 + st_srccol,
              (char*)Asm_ + c * 1024 + lane * 16);
      int brow = nt * 128 + lrow;
      gload16(B + (size_t)brow * ldb + k0 + st_srccol,
              (char*)Bsm_ + c * 1024 + lane * 16);
    }
    __syncthreads();
#pragma unroll
    for (int kk = 0; kk < 2; ++kk) {
      int cb = (kk * 64 + ((lane >> 4) << 4)) ^ ((lane & 7) << 4);
      s16x8 af[4], bfr[4];
#pragma unroll
      for (int m = 0; m < 4; ++m)
        af[m] = *(const s16x8*)((const char*)Asm_ + (wr * 64 + m * 16 + (lane & 15)) * 128 + cb);
#pragma unroll
      for (int n = 0; n < 4; ++n)
        bfr[n] = *(const s16x8*)((const char*)Bsm_ + (wc * 64 + n * 16 + (lane & 15)) * 128 + cb);
#pragma unroll
      for (int m = 0; m < 4; ++m)
#pragma unroll
        for (int n = 0; n < 4; ++n)
          acc[m][n] = __builtin_amdgcn_mfma_f32_16x16x32_bf16(af[m], bfr[n], acc[m][n], 0, 0, 0);
    }
  }
  const int rb = mt * 128 + wr * 64, cbse = nt * 128 + wc * 64;
#pragma unroll
  for (int m = 0; m < 4; ++m) {
#pragma unroll
    for (int n = 0; n < 4; ++n) {
#pragma unroll
      for (int rg = 0; rg < 4; ++rg) {
        int rr = rb + m * 16 + ((lane >> 4) << 2) + rg;
        int cc = cbse + n * 16 + (lane & 15);
        if (rr < M) {
          float v = acc[m][n][rg];
          if (MODE == 1) {
            v += bias[cc];
            ((float*)Cout)[(size_t)rr * N + cc] = v;
          } else {
            int hd = cc >> 7;
            float lsum = lbuf[(size_t)rr * 12 + hd];
            float osum = o0buf[(size_t)rr * N + cc];
            for (int s = 1; s < nsplit; ++s) {
              lsum += lbuf[((size_t)s * M + rr) * 12 + hd];
              osum += o1buf[(size_t)(s - 1) * M * 1536 + (size_t)rr * N + cc];
            }
            v = v * zbuf[(size_t)rr * 12 + hd] + osum * (1.0f / lsum) + bias[cc & 127];
            ((unsigned short*)Cout)[(size_t)rr * N + cc] = f2bf(v);
          }
        }
      }
    }
  }
}

// ---------------- RMS + RoPE (+ z for the q path); input row stride ld ----------------
__global__ __launch_bounds__(256) void rms_rope_kernel(
    const unsigned short* __restrict__ pre, const float* __restrict__ freqs,
    const float* __restrict__ g, const float* __restrict__ g_kmean,
    unsigned short* __restrict__ outr, float* __restrict__ zout,
    int S, int ld, float oscale,
    const int* __restrict__ hgp, const int* __restrict__ wgp) {
  const int s = blockIdx.x;
  const int tid = threadIdx.x;
  const int lane = tid & 63, wid = tid >> 6;
  const unsigned short* row = pre + (size_t)s * ld;
  unsigned int pv0, pv1, pv2;
  float ssq = 0.f;
  {
    pv0 = *(const unsigned int*)(row + 2 * (tid));
    pv1 = *(const unsigned int*)(row + 2 * (tid + 256));
    pv2 = *(const unsigned int*)(row + 2 * (tid + 512));
    float a0 = bf2f((unsigned short)(pv0 & 0xffffu)), b0 = bf2f((unsigned short)(pv0 >> 16));
    float a1 = bf2f((unsigned short)(pv1 & 0xffffu)), b1 = bf2f((unsigned short)(pv1 >> 16));
    float a2 = bf2f((unsigned short)(pv2 & 0xffffu)), b2 = bf2f((unsigned short)(pv2 >> 16));
    ssq = a0 * a0 + b0 * b0 + a1 * a1 + b1 * b1 + a2 * a2 + b2 * b2;
  }
#pragma unroll
  for (int m = 1; m < 64; m <<= 1) ssq += __shfl_xor(ssq, m, 64);
  __shared__ float wpart[4];
  if (lane == 0) wpart[wid] = ssq;
  __syncthreads();
  float tot = wpart[0] + wpart[1] + wpart[2] + wpart[3];
  float rms = rsqrtf(tot * (1.0f / 1536.0f) + 1e-6f);
  const int Wg = *wgp;
  const int HWg = (*hgp) * Wg;
  int fi = s / HWg; int rem = s - fi * HWg;
  int hi = rem / Wg; int wi = rem - hi * Wg;
  unsigned int pvs[3] = {pv0, pv1, pv2};
#pragma unroll
  for (int rd = 0; rd < 3; ++rd) {
    int p = tid + rd * 256;
    int c = p & 63;
    int fidx = (c < 22) ? fi : ((c < 43) ? hi : wi);
    float cr = freqs[fidx * 128 + 2 * c];
    float ci = freqs[fidx * 128 + 2 * c + 1];
    float xr = bf2f((unsigned short)(pvs[rd] & 0xffffu)) * rms * g[2 * p];
    float xi = bf2f((unsigned short)(pvs[rd] >> 16)) * rms * g[2 * p + 1];
    float yr = (xr * cr - xi * ci) * oscale;
    float yi = (xr * ci + xi * cr) * oscale;
    unsigned int ow = (unsigned int)f2bf(yr) | ((unsigned int)f2bf(yi) << 16);
    *(unsigned int*)(outr + (size_t)s * 1536 + 2 * p) = ow;
    if (zout != nullptr) {
      int head = p >> 6;
      float part = fmaxf(xr, 0.f) * g_kmean[head * 128 + 2 * c] +
                   fmaxf(xi, 0.f) * g_kmean[head * 128 + 2 * c + 1];
#pragma unroll
      for (int m = 1; m < 64; m <<= 1) part += __shfl_xor(part, m, 64);
      if (lane == 0) zout[(size_t)s * 12 + head] = 1.0f / (part + 1e-6f);
    }
  }
}

// ---------------- V transpose: vpre (S, ld cols used 64) bf16 -> vt (1536, S) bf16 ----------------
__global__ __launch_bounds__(256) void vtrans_kernel(const unsigned short* __restrict__ vpre,
                                                     unsigned short* __restrict__ vt, int S, int ld) {
  __shared__ unsigned short tile[64][66];
  int t0 = blockIdx.x * 64, c0 = blockIdx.y * 64;
  int tid = threadIdx.x;
#pragma unroll
  for (int rep = 0; rep < 16; ++rep) {
    int lin = rep * 256 + tid;
    int i = lin >> 6, j = lin & 63;
    int t = t0 + i; if (t > S - 1) t = S - 1;
    tile[i][j] = vpre[(size_t)t * ld + c0 + j];
  }
  __syncthreads();
#pragma unroll
  for (int rep = 0; rep < 16; ++rep) {
    int lin = rep * 256 + tid;
    int j = lin >> 6, i = lin & 63;
    int t = t0 + i;
    if (t < S) vt[(size_t)(c0 + j) * S + t] = tile[i][j];
  }
}

// ---------------- Flash attention, 32x32 MFMA, in-register P (permlane32_swap), ----------
// ---------------- no-max softmax, KV-split x nsplit, KVBLK=32 (R9-verbatim) --------------
__global__ __launch_bounds__(256, 3) void attn_kernel(
    const unsigned short* __restrict__ rq, const unsigned short* __restrict__ rk,
    const unsigned short* __restrict__ vt, float* __restrict__ o0buf,
    float* __restrict__ o1buf, float* __restrict__ lbuf, int S, int nqb, int nsplit) {
  __shared__ __align__(16) unsigned short Ks[2][32 * 128];
  __shared__ __align__(16) unsigned short Vs[2][128 * 32];
  const int tid = threadIdx.x, wid = tid >> 6, lane = tid & 63;
  const int q32 = lane & 31, hi = lane >> 5;

  const int total = nqb * 12 * nsplit;
  int lg = blockIdx.x;
  if ((total & 7) == 0) lg = (lg & 7) * (total >> 3) + (lg >> 3);
  const int z = lg / (nqb * 12);
  int rem = lg - z * nqb * 12;
  const int h = rem / nqb;
  const int qb = rem - h * nqb;
  const int q0 = qb * 128 + wid * 32;

  const int seg = (((S + nsplit - 1) / nsplit) + 31) & ~31;
  const int tbeg = z * seg;
  const int tend = (tbeg + seg < S) ? (tbeg + seg) : S;
  float* obufz = (z == 0) ? o0buf : (o1buf + (size_t)(z - 1) * S * 1536);
  float* lbufz = lbuf + (size_t)z * S * 12;

  s16x8 qf[8];
  {
    int qrow = q0 + q32; if (qrow > S - 1) qrow = S - 1;
    const unsigned short* qp = rq + (size_t)qrow * 1536 + h * 128 + hi * 8;
#pragma unroll
    for (int dblk = 0; dblk < 8; ++dblk) qf[dblk] = *(const s16x8*)(qp + dblk * 16);
  }
  f32x16 o0 = {}, o1 = {}, o2 = {}, o3 = {};
  float lsum = 0.f;

  const int k_tok0 = tid >> 4;
  const int k_off = (tid & 15) * 16;
  const int v_d0 = tid >> 2;
  const int v_toff = (tid & 3) * 16;
  const int vswz = ((q32 >> 1) & 3) << 4;

#define STAGE(buf, t0s)                                                            \
  {                                                                                \
    _Pragma("unroll") for (int r = 0; r < 2; ++r) {                                \
      int ktok = k_tok0 + 16 * r;                                                  \
      int kb = k_off ^ ((ktok & 7) << 4);                                          \
      int trow = (t0s) + ktok; if (trow > S - 1) trow = S - 1;                     \
      gload16(rk + (size_t)trow * 1536 + h * 128 + (kb >> 1),                      \
              (char*)Ks[buf] + r * 4096 + tid * 16);                               \
      int dd = v_d0 + 64 * r;                                                      \
      int vb_ = v_toff ^ (((dd >> 1) & 3) << 4);                                   \
      int vtok = (t0s) + (vb_ >> 1); if (vtok > S - 8) vtok = S - 8;               \
      gload16(vt + (size_t)(h * 128 + dd) * S + vtok,                              \
              (char*)Vs[buf] + r * 4096 + tid * 16);                               \
    }                                                                              \
  }

  STAGE(0, tbeg);
  __syncthreads();
  int cur = 0;
  for (int t0 = tbeg; t0 < tend; t0 += 32) {
    if (t0 + 32 < tend) STAGE(cur ^ 1, t0 + 32);
    f32x16 sc = {};
    __builtin_amdgcn_s_setprio(1);
#pragma unroll
    for (int dblk = 0; dblk < 8; ++dblk) {
      s16x8 kfr = *(const s16x8*)((const char*)Ks[cur] + q32 * 256 +
                                  ((dblk * 32 + hi * 16) ^ ((q32 & 7) << 4)));
      sc = __builtin_amdgcn_mfma_f32_32x32x16_bf16(kfr, qf[dblk], sc, 0, 0, 0);
    }
    __builtin_amdgcn_s_setprio(0);
    const bool full = (t0 + 32 <= tend);
    unsigned int pk[8];
    float rs = 0.f;
#pragma unroll
    for (int j = 0; j < 8; ++j) {
      float p0, p1;
      if (full) {
        p0 = fast_exp2(sc[2 * j]);
        p1 = fast_exp2(sc[2 * j + 1]);
      } else {
        int r0 = 2 * j;
        int tk0 = t0 + (r0 & 3) + 8 * (r0 >> 2) + 4 * hi;
        p0 = (tk0 < tend) ? fast_exp2(sc[2 * j]) : 0.f;
        p1 = (tk0 + 1 < tend) ? fast_exp2(sc[2 * j + 1]) : 0.f;
      }
      unsigned int u0 = __float_as_uint(p0) & 0xffff0000u;
      unsigned int u1 = __float_as_uint(p1) & 0xffff0000u;
      rs += __uint_as_float(u0) + __uint_as_float(u1);
      pk[j] = (u0 >> 16) | u1;
    }
    lsum += rs;
    unsigned int x0 = pk[0], y0 = pk[2], x1 = pk[1], y1 = pk[3];
    asm("v_permlane32_swap_b32 %0, %1" : "+v"(x0), "+v"(y0));
    asm("v_permlane32_swap_b32 %0, %1" : "+v"(x1), "+v"(y1));
    unsigned int x2 = pk[4], y2 = pk[6], x3 = pk[5], y3 = pk[7];
    asm("v_permlane32_swap_b32 %0, %1" : "+v"(x2), "+v"(y2));
    asm("v_permlane32_swap_b32 %0, %1" : "+v"(x3), "+v"(y3));
    u32x4 pa0v = {x0, x1, y0, y1};
    u32x4 pa1v = {x2, x3, y2, y3};
    s16x8 pa0 = __builtin_bit_cast(s16x8, pa0v);
    s16x8 pa1 = __builtin_bit_cast(s16x8, pa1v);
    __builtin_amdgcn_s_setprio(1);
#pragma unroll
    for (int ks = 0; ks < 2; ++ks) {
      s16x8 pa = ks ? pa1 : pa0;
      const int tb = (ks * 32 + hi * 16) ^ vswz;
      const char* vbase = (const char*)Vs[cur] + q32 * 64 + tb;
      s16x8 vb;
      vb = *(const s16x8*)(vbase + 0 * 2048);
      o0 = __builtin_amdgcn_mfma_f32_32x32x16_bf16(pa, vb, o0, 0, 0, 0);
      vb = *(const s16x8*)(vbase + 1 * 2048);
      o1 = __builtin_amdgcn_mfma_f32_32x32x16_bf16(pa, vb, o1, 0, 0, 0);
      vb = *(const s16x8*)(vbase + 2 * 2048);
      o2 = __builtin_amdgcn_mfma_f32_32x32x16_bf16(pa, vb, o2, 0, 0, 0);
      vb = *(const s16x8*)(vbase + 3 * 2048);
      o3 = __builtin_amdgcn_mfma_f32_32x32x16_bf16(pa, vb, o3, 0, 0, 0);
    }
    __builtin_amdgcn_s_setprio(0);
    __syncthreads();
    cur ^= 1;
  }
  lsum += __shfl_xor(lsum, 32, 64);
  {
    int qrow = q0 + q32;
    if (hi == 0 && qrow < S) lbufz[(size_t)qrow * 12 + h] = lsum;
  }
#pragma unroll
  for (int r = 0; r < 16; ++r) {
    int qrow = q0 + (r & 3) + 8 * (r >> 2) + 4 * hi;
    if (qrow < S) {
      float* orow = obufz + (size_t)qrow * 1536 + h * 128 + q32;
      orow[0] = o0[r]; orow[32] = o1[r]; orow[64] = o2[r]; orow[96] = o3[r];
    }
  }
#undef STAGE
}

extern "C" void kernel_launch(void* const* d_in, const int* in_sizes, int n_in,
                              void* d_out, int out_size, void* d_ws, size_t ws_size,
                              hipStream_t stream) {
  const float* x = (const float*)d_in[0];
  const float* freqs = (const float*)d_in[1];
  const float* g_kmean = (const float*)d_in[2];
  const float* g_kv = (const float*)d_in[3];
  const float* Wq = (const float*)d_in[4];  const float* bq = (const float*)d_in[5];
  const float* Wk = (const float*)d_in[6];  const float* bk = (const float*)d_in[7];
  const float* Wv = (const float*)d_in[8];  const float* bv = (const float*)d_in[9];
  const float* Wo = (const float*)d_in[10]; const float* bo = (const float*)d_in[11];
  const float* gq = (const float*)d_in[12]; const float* gk = (const float*)d_in[13];
  const float* Wlin = (const float*)d_in[14]; const float* blin = (const float*)d_in[15];
  const int* hgp = (const int*)d_in[17];
  const int* wgp = (const int*)d_in[18];

  const int S = in_sizes[0] / 1536;
  const int nsplit = 2;

  char* ws = (char*)d_ws;
  const size_t SZ = (size_t)S * 1536 * 2;        // bf16 (S,1536)
  const size_t OSZ = (size_t)S * 1536 * 4;       // f32 (S,1536) partial
  const size_t WSZ = (size_t)1536 * 1536 * 2;    // bf16 1536^2
  const size_t QKVSZ = (size_t)S * 4608 * 2;     // bf16 (S,4608)
  const size_t G2SZ = (size_t)12 * 128 * 128 * 2;
  size_t o_xbf = 0;
  size_t o_wqkv = o_xbf + SZ;
  size_t o_wo = o_wqkv + 3 * WSZ;
  size_t o_g2 = o_wo + WSZ;
  size_t o_qkv = o_g2 + G2SZ;
  size_t o_rk = o_qkv + QKVSZ;
  size_t o_vt = o_rk + SZ;
  size_t o_z = o_vt + SZ;
  size_t o_bqkv = o_z + (size_t)S * 12 * 4;
  size_t o_o1 = o_bqkv + 4608 * 4;
  size_t o_l = o_o1 + (size_t)(nsplit - 1) * OSZ;
  size_t need = o_l + (size_t)nsplit * S * 12 * 4;
  if (ws_size < need) return;

  unsigned short* xbf = (unsigned short*)(ws + o_xbf);
  unsigned short* wqkv = (unsigned short*)(ws + o_wqkv);
  unsigned short* wob = (unsigned short*)(ws + o_wo);
  unsigned short* g2c = (unsigned short*)(ws + o_g2);
  unsigned short* qkv = (unsigned short*)(ws + o_qkv);
  unsigned short* rkb = (unsigned short*)(ws + o_rk);
  unsigned short* vtb = (unsigned short*)(ws + o_vt);
  float* zbuf = (float*)(ws + o_z);
  float* bqkv = (float*)(ws + o_bqkv);
  unsigned short* rqb = xbf;
  float* o0buf = (float*)(ws + o_qkv);
  float* o1buf = (float*)(ws + o_o1);
  float* lbuf = (float*)(ws + o_l);
  unsigned short* ybf = (unsigned short*)(ws + o_qkv + OSZ);

  // 1) casts
  {
    int n4 = (S * 1536) / 4;
    cast_f32_bf16_x4<<<(n4 + 255) / 256, 256, 0, stream>>>(x, xbf, n4);
    int w4 = (1536 * 1536) / 4;
    int wg = (w4 + 255) / 256;
    cast_f32_bf16_x4<<<wg, 256, 0, stream>>>(Wq, wqkv, w4);
    cast_f32_bf16_x4<<<wg, 256, 0, stream>>>(Wk, wqkv + (size_t)1536 * 1536, w4);
    cast_f32_bf16_x4<<<wg, 256, 0, stream>>>(Wv, wqkv + (size_t)2 * 1536 * 1536, w4);
    cast_f32_bf16_x4<<<wg, 256, 0, stream>>>(Wo, wob, w4);
  }
  hipMemcpyAsync(bqkv, bq, 1536 * 4, hipMemcpyDeviceToDevice, stream);
  hipMemcpyAsync(bqkv + 1536, bk, 1536 * 4, hipMemcpyDeviceToDevice, stream);
  hipMemcpyAsync(bqkv + 3072, bv, 1536 * 4, hipMemcpyDeviceToDevice, stream);

  // 2) compact block-diagonal G2c
  g2fill_kernel<<<dim3(12, 128), 128, 0, stream>>>(g_kv, Wlin, g2c);

  // 3) merged QKV projection via 256^2 8-phase GEMM: qkv[S][4608]
  {
    dim3 ggrid((S + 255) / 256, 4608 / 256);
    gemm256_bt<<<ggrid, 512, 0, stream>>>(xbf, wqkv, bqkv, qkv, S, 4608, 1536);
  }

  // 4) RMS + RoPE (+z for q)
  rms_rope_kernel<<<S, 256, 0, stream>>>(qkv, freqs, gq, g_kmean, rqb, zbuf, S, 4608, QSCALE, hgp, wgp);
  rms_rope_kernel<<<S, 256, 0, stream>>>(qkv + 1536, freqs, gk, nullptr, rkb, nullptr, S, 4608, 1.0f, hgp, wgp);

  // 5) V transpose
  vtrans_kernel<<<dim3((S + 63) / 64, 24), 256, 0, stream>>>(qkv + 3072, vtb, S, 4608);

  // 6) attention, KV-split x nsplit
  {
    int nqb = (S + 127) / 128;
    attn_kernel<<<dim3(nqb * 12 * nsplit), 256, 0, stream>>>(rqb, rkb, vtb,
                                                             o0buf, o1buf, lbuf, S, nqb, nsplit);
  }

  // 7) xg merge (block-diag, K=128) -> ybf ; 8) out GEMM
  {
    dim3 ggrid((S + 127) / 128, 12);
    gemm_bt<3><<<ggrid, 256, 0, stream>>>(rqb, g2c, blin, ybf, S, 1536, 128, 1536, 128,
                                          o0buf, zbuf, o1buf, lbuf, nsplit);
    gemm_bt<1><<<ggrid, 256, 0, stream>>>(ybf, wob, bo, (float*)d_out, S, 1536, 1536, 1536, 1536,
                                          nullptr, nullptr, nullptr, nullptr, 0);
  }
}

// Round 15
// 408.358 us; speedup vs baseline: 1.1832x; 1.1832x over previous
//
#include <hip/hip_runtime.h>

typedef short s16x8 __attribute__((ext_vector_type(8)));
typedef float f32x4 __attribute__((ext_vector_type(4)));
typedef float f32x16 __attribute__((ext_vector_type(16)));
typedef unsigned short u16x4 __attribute__((ext_vector_type(4)));
typedef unsigned int u32x4 __attribute__((ext_vector_type(4)));

#define QSCALE (0.08838834764831845f * 1.4426950408889634f)

__device__ __forceinline__ unsigned short f2bf(float f) {
  unsigned int u = __float_as_uint(f);
  u += 0x7fffu + ((u >> 16) & 1u);
  return (unsigned short)(u >> 16);
}
__device__ __forceinline__ float bf2f(unsigned short h) {
  return __uint_as_float((unsigned int)h << 16);
}
__device__ __forceinline__ float fast_exp2(float x) {
  float r;
  asm("v_exp_f32 %0, %1" : "=v"(r) : "v"(x));
  return r;
}

__device__ __forceinline__ void gload16(const void* gp, void* lp) {
  __builtin_amdgcn_global_load_lds(
      (const __attribute__((address_space(1))) void*)gp,
      (__attribute__((address_space(3))) void*)lp,
      16, 0, 0);
}

// ---------------- cast f32 -> bf16, 4 at a time ----------------
__global__ void cast_f32_bf16_x4(const float* __restrict__ in,
                                 unsigned short* __restrict__ out, int n4) {
  int i = blockIdx.x * 256 + threadIdx.x;
  if (i >= n4) return;
  f32x4 v = *((const f32x4*)in + i);
  u16x4 o;
  o[0] = f2bf(v[0]); o[1] = f2bf(v[1]); o[2] = f2bf(v[2]); o[3] = f2bf(v[3]);
  *((u16x4*)out + i) = o;
}

// ---------------- fused weight cast: Wq|Wk|Wv|Wo -> contiguous bf16 dst ----------------
__global__ void cast_weights4(const float* __restrict__ Wq, const float* __restrict__ Wk,
                              const float* __restrict__ Wv, const float* __restrict__ Wo,
                              unsigned short* __restrict__ dst, int per4) {
  int i = blockIdx.x * 256 + threadIdx.x;
  if (i >= 4 * per4) return;
  int m = i / per4;
  int off = i - m * per4;
  const float* src = (m == 0) ? Wq : (m == 1) ? Wk : (m == 2) ? Wv : Wo;
  f32x4 v = *((const f32x4*)src + off);
  u16x4 o;
  o[0] = f2bf(v[0]); o[1] = f2bf(v[1]); o[2] = f2bf(v[2]); o[3] = f2bf(v[3]);
  *((u16x4*)dst + i) = o;
}

// ---------------- compact G2c[h*128+m][d] = (1/QSCALE) * sum_j g_kv[h][d][j]*Wlin[m][j] ----
__global__ void g2fill_kernel(const float* __restrict__ g_kv,
                              const float* __restrict__ Wlin,
                              unsigned short* __restrict__ G2c) {
  int h = blockIdx.x, m = blockIdx.y, d = threadIdx.x;
  const float* gk = g_kv + ((size_t)h * 128 + d) * 128;
  const float* wl = Wlin + (size_t)m * 128;
  float s = 0.f;
  for (int j = 0; j < 128; ++j) s += gk[j] * wl[j];
  G2c[((size_t)h * 128 + m) * 128 + d] = f2bf(s * (1.0f / QSCALE));
}

// ---------------- GEMM: C[M,N] = A[M,K] @ B[N,K]^T (+ epilogue) ----------------
// MODE 0: bf16 out, +bias[cc]
// MODE 1: f32 out, +bias[cc]
// MODE 3: block-diag per-head (A col offset nt*128, compact B), NSPLIT-way merge epilogue
template <int MODE, int NSPLIT>
__global__ __launch_bounds__(256) void gemm_bt(
    const unsigned short* __restrict__ A, const unsigned short* __restrict__ B,
    const float* __restrict__ bias, void* __restrict__ Cout,
    int M, int N, int K, int lda, int ldb,
    const float* __restrict__ o0buf, const float* __restrict__ zbuf,
    const float* __restrict__ o1buf, const float* __restrict__ lbuf) {
  __shared__ __align__(16) unsigned short Asm_[128 * 64];
  __shared__ __align__(16) unsigned short Bsm_[128 * 64];
  const int tid = threadIdx.x;
  const int wid = tid >> 6, lane = tid & 63;
  const int mt = blockIdx.x, nt = blockIdx.y;
  const int wr = wid >> 1, wc = wid & 1;
  const int acol = (MODE == 3) ? nt * 128 : 0;
  f32x4 acc[4][4] = {};

  const int st_srccol = ((((lane & 7) << 4) ^ ((lane >> 3) << 4)) >> 1);  // elements
  const int st_rowoff = (lane >> 3);

  for (int k0 = 0; k0 < K; k0 += 64) {
    __syncthreads();
#pragma unroll
    for (int r = 0; r < 4; ++r) {
      int c = wid * 4 + r;
      int lrow = c * 8 + st_rowoff;
      int arow = mt * 128 + lrow; if (arow > M - 1) arow = M - 1;
      gload16(A + (size_t)arow * lda + acol + k0 + st_srccol,
              (char*)Asm_ + c * 1024 + lane * 16);
      int brow = nt * 128 + lrow;
      gload16(B + (size_t)brow * ldb + k0 + st_srccol,
              (char*)Bsm_ + c * 1024 + lane * 16);
    }
    __syncthreads();
#pragma unroll
    for (int kk = 0; kk < 2; ++kk) {
      int cb = (kk * 64 + ((lane >> 4) << 4)) ^ ((lane & 7) << 4);
      s16x8 af[4], bfr[4];
#pragma unroll
      for (int m = 0; m < 4; ++m)
        af[m] = *(const s16x8*)((const char*)Asm_ + (wr * 64 + m * 16 + (lane & 15)) * 128 + cb);
#pragma unroll
      for (int n = 0; n < 4; ++n)
        bfr[n] = *(const s16x8*)((const char*)Bsm_ + (wc * 64 + n * 16 + (lane & 15)) * 128 + cb);
#pragma unroll
      for (int m = 0; m < 4; ++m)
#pragma unroll
        for (int n = 0; n < 4; ++n)
          acc[m][n] = __builtin_amdgcn_mfma_f32_16x16x32_bf16(af[m], bfr[n], acc[m][n], 0, 0, 0);
    }
  }
  const int rb = mt * 128 + wr * 64, cbse = nt * 128 + wc * 64;
#pragma unroll
  for (int m = 0; m < 4; ++m) {
#pragma unroll
    for (int n = 0; n < 4; ++n) {
#pragma unroll
      for (int rg = 0; rg < 4; ++rg) {
        int rr = rb + m * 16 + ((lane >> 4) << 2) + rg;
        int cc = cbse + n * 16 + (lane & 15);
        if (rr < M) {
          float v = acc[m][n][rg];
          if (MODE == 0) {
            v += bias[cc];
            ((unsigned short*)Cout)[(size_t)rr * N + cc] = f2bf(v);
          } else if (MODE == 1) {
            v += bias[cc];
            ((float*)Cout)[(size_t)rr * N + cc] = v;
          } else {
            int hd = cc >> 7;
            float lsum = lbuf[(size_t)rr * 12 + hd];
            float osum = o0buf[(size_t)rr * N + cc];
#pragma unroll
            for (int s = 1; s < NSPLIT; ++s) {
              lsum += lbuf[((size_t)s * M + rr) * 12 + hd];
              osum += o1buf[(size_t)(s - 1) * M * 1536 + (size_t)rr * N + cc];
            }
            v = v * zbuf[(size_t)rr * 12 + hd] + osum * (1.0f / lsum) + bias[cc & 127];
            ((unsigned short*)Cout)[(size_t)rr * N + cc] = f2bf(v);
          }
        }
      }
    }
  }
}

// ---------------- fused RMS + RoPE for q (blockIdx.y==0) and k (blockIdx.y==1) -----------
__global__ __launch_bounds__(256) void rms_rope_kernel(
    const unsigned short* __restrict__ qkv, const float* __restrict__ freqs,
    const float* __restrict__ gq, const float* __restrict__ gk,
    const float* __restrict__ g_kmean,
    unsigned short* __restrict__ rqb, unsigned short* __restrict__ rkb,
    float* __restrict__ zbuf, int S,
    const int* __restrict__ hgp, const int* __restrict__ wgp) {
  const int s = blockIdx.x;
  const int isk = blockIdx.y;
  const unsigned short* row = qkv + (size_t)s * 4608 + (isk ? 1536 : 0);
  const float* g = isk ? gk : gq;
  unsigned short* outr = isk ? rkb : rqb;
  float* zout = isk ? nullptr : zbuf;
  const float oscale = isk ? 1.0f : QSCALE;
  const int tid = threadIdx.x;
  const int lane = tid & 63, wid = tid >> 6;
  unsigned int pv0, pv1, pv2;
  float ssq = 0.f;
  {
    pv0 = *(const unsigned int*)(row + 2 * (tid));
    pv1 = *(const unsigned int*)(row + 2 * (tid + 256));
    pv2 = *(const unsigned int*)(row + 2 * (tid + 512));
    float a0 = bf2f((unsigned short)(pv0 & 0xffffu)), b0 = bf2f((unsigned short)(pv0 >> 16));
    float a1 = bf2f((unsigned short)(pv1 & 0xffffu)), b1 = bf2f((unsigned short)(pv1 >> 16));
    float a2 = bf2f((unsigned short)(pv2 & 0xffffu)), b2 = bf2f((unsigned short)(pv2 >> 16));
    ssq = a0 * a0 + b0 * b0 + a1 * a1 + b1 * b1 + a2 * a2 + b2 * b2;
  }
#pragma unroll
  for (int m = 1; m < 64; m <<= 1) ssq += __shfl_xor(ssq, m, 64);
  __shared__ float wpart[4];
  if (lane == 0) wpart[wid] = ssq;
  __syncthreads();
  float tot = wpart[0] + wpart[1] + wpart[2] + wpart[3];
  float rms = rsqrtf(tot * (1.0f / 1536.0f) + 1e-6f);
  const int Wg = *wgp;
  const int HWg = (*hgp) * Wg;
  int fi = s / HWg; int rem = s - fi * HWg;
  int hi = rem / Wg; int wi = rem - hi * Wg;
  unsigned int pvs[3] = {pv0, pv1, pv2};
#pragma unroll
  for (int rd = 0; rd < 3; ++rd) {
    int p = tid + rd * 256;
    int c = p & 63;
    int fidx = (c < 22) ? fi : ((c < 43) ? hi : wi);
    float cr = freqs[fidx * 128 + 2 * c];
    float ci = freqs[fidx * 128 + 2 * c + 1];
    float xr = bf2f((unsigned short)(pvs[rd] & 0xffffu)) * rms * g[2 * p];
    float xi = bf2f((unsigned short)(pvs[rd] >> 16)) * rms * g[2 * p + 1];
    float yr = (xr * cr - xi * ci) * oscale;
    float yi = (xr * ci + xi * cr) * oscale;
    unsigned int ow = (unsigned int)f2bf(yr) | ((unsigned int)f2bf(yi) << 16);
    *(unsigned int*)(outr + (size_t)s * 1536 + 2 * p) = ow;
    if (zout != nullptr) {
      int head = p >> 6;
      float part = fmaxf(xr, 0.f) * g_kmean[head * 128 + 2 * c] +
                   fmaxf(xi, 0.f) * g_kmean[head * 128 + 2 * c + 1];
#pragma unroll
      for (int m = 1; m < 64; m <<= 1) part += __shfl_xor(part, m, 64);
      if (lane == 0) zout[(size_t)s * 12 + head] = 1.0f / (part + 1e-6f);
    }
  }
}

// ---------------- V transpose: vpre (S, ld cols used 64) bf16 -> vt (1536, S) bf16 ----------------
__global__ __launch_bounds__(256) void vtrans_kernel(const unsigned short* __restrict__ vpre,
                                                     unsigned short* __restrict__ vt, int S, int ld) {
  __shared__ unsigned short tile[64][66];
  int t0 = blockIdx.x * 64, c0 = blockIdx.y * 64;
  int tid = threadIdx.x;
#pragma unroll
  for (int rep = 0; rep < 16; ++rep) {
    int lin = rep * 256 + tid;
    int i = lin >> 6, j = lin & 63;
    int t = t0 + i; if (t > S - 1) t = S - 1;
    tile[i][j] = vpre[(size_t)t * ld + c0 + j];
  }
  __syncthreads();
#pragma unroll
  for (int rep = 0; rep < 16; ++rep) {
    int lin = rep * 256 + tid;
    int j = lin >> 6, i = lin & 63;
    int t = t0 + i;
    if (t < S) vt[(size_t)(c0 + j) * S + t] = tile[i][j];
  }
}

// ---------------- Flash attention, 32x32 MFMA, in-register P (permlane32_swap), ----------
// ---------------- no-max softmax, KV-split x nsplit, KVBLK=32 (R9-VERBATIM) --------------
__global__ __launch_bounds__(256, 3) void attn_kernel(
    const unsigned short* __restrict__ rq, const unsigned short* __restrict__ rk,
    const unsigned short* __restrict__ vt, float* __restrict__ o0buf,
    float* __restrict__ o1buf, float* __restrict__ lbuf, int S, int nqb, int nsplit) {
  __shared__ __align__(16) unsigned short Ks[2][32 * 128];
  __shared__ __align__(16) unsigned short Vs[2][128 * 32];
  const int tid = threadIdx.x, wid = tid >> 6, lane = tid & 63;
  const int q32 = lane & 31, hi = lane >> 5;

  const int total = nqb * 12 * nsplit;
  int lg = blockIdx.x;
  if ((total & 7) == 0) lg = (lg & 7) * (total >> 3) + (lg >> 3);
  const int z = lg / (nqb * 12);
  int rem = lg - z * nqb * 12;
  const int h = rem / nqb;
  const int qb = rem - h * nqb;
  const int q0 = qb * 128 + wid * 32;

  const int seg = (((S + nsplit - 1) / nsplit) + 31) & ~31;
  const int tbeg = z * seg;
  const int tend = (tbeg + seg < S) ? (tbeg + seg) : S;
  float* obufz = (z == 0) ? o0buf : (o1buf + (size_t)(z - 1) * S * 1536);
  float* lbufz = lbuf + (size_t)z * S * 12;

  s16x8 qf[8];
  {
    int qrow = q0 + q32; if (qrow > S - 1) qrow = S - 1;
    const unsigned short* qp = rq + (size_t)qrow * 1536 + h * 128 + hi * 8;
#pragma unroll
    for (int dblk = 0; dblk < 8; ++dblk) qf[dblk] = *(const s16x8*)(qp + dblk * 16);
  }
  f32x16 o0 = {}, o1 = {}, o2 = {}, o3 = {};
  float lsum = 0.f;

  const int k_tok0 = tid >> 4;
  const int k_off = (tid & 15) * 16;
  const int v_d0 = tid >> 2;
  const int v_toff = (tid & 3) * 16;
  const int vswz = ((q32 >> 1) & 3) << 4;

#define STAGE(buf, t0s)                                                            \
  {                                                                                \
    _Pragma("unroll") for (int r = 0; r < 2; ++r) {                                \
      int ktok = k_tok0 + 16 * r;                                                  \
      int kb = k_off ^ ((ktok & 7) << 4);                                          \
      int trow = (t0s) + ktok; if (trow > S - 1) trow = S - 1;                     \
      gload16(rk + (size_t)trow * 1536 + h * 128 + (kb >> 1),                      \
              (char*)Ks[buf] + r * 4096 + tid * 16);                               \
      int dd = v_d0 + 64 * r;                                                      \
      int vb_ = v_toff ^ (((dd >> 1) & 3) << 4);                                   \
      int vtok = (t0s) + (vb_ >> 1); if (vtok > S - 8) vtok = S - 8;               \
      gload16(vt + (size_t)(h * 128 + dd) * S + vtok,                              \
              (char*)Vs[buf] + r * 4096 + tid * 16);                               \
    }                                                                              \
  }

  STAGE(0, tbeg);
  __syncthreads();
  int cur = 0;
  for (int t0 = tbeg; t0 < tend; t0 += 32) {
    if (t0 + 32 < tend) STAGE(cur ^ 1, t0 + 32);
    f32x16 sc = {};
    __builtin_amdgcn_s_setprio(1);
#pragma unroll
    for (int dblk = 0; dblk < 8; ++dblk) {
      s16x8 kfr = *(const s16x8*)((const char*)Ks[cur] + q32 * 256 +
                                  ((dblk * 32 + hi * 16) ^ ((q32 & 7) << 4)));
      sc = __builtin_amdgcn_mfma_f32_32x32x16_bf16(kfr, qf[dblk], sc, 0, 0, 0);
    }
    __builtin_amdgcn_s_setprio(0);
    const bool full = (t0 + 32 <= tend);
    unsigned int pk[8];
    float rs = 0.f;
#pragma unroll
    for (int j = 0; j < 8; ++j) {
      float p0, p1;
      if (full) {
        p0 = fast_exp2(sc[2 * j]);
        p1 = fast_exp2(sc[2 * j + 1]);
      } else {
        int r0 = 2 * j;
        int tk0 = t0 + (r0 & 3) + 8 * (r0 >> 2) + 4 * hi;
        p0 = (tk0 < tend) ? fast_exp2(sc[2 * j]) : 0.f;
        p1 = (tk0 + 1 < tend) ? fast_exp2(sc[2 * j + 1]) : 0.f;
      }
      unsigned int u0 = __float_as_uint(p0) & 0xffff0000u;
      unsigned int u1 = __float_as_uint(p1) & 0xffff0000u;
      rs += __uint_as_float(u0) + __uint_as_float(u1);
      pk[j] = (u0 >> 16) | u1;
    }
    lsum += rs;
    unsigned int x0 = pk[0], y0 = pk[2], x1 = pk[1], y1 = pk[3];
    asm("v_permlane32_swap_b32 %0, %1" : "+v"(x0), "+v"(y0));
    asm("v_permlane32_swap_b32 %0, %1" : "+v"(x1), "+v"(y1));
    unsigned int x2 = pk[4], y2 = pk[6], x3 = pk[5], y3 = pk[7];
    asm("v_permlane32_swap_b32 %0, %1" : "+v"(x2), "+v"(y2));
    asm("v_permlane32_swap_b32 %0, %1" : "+v"(x3), "+v"(y3));
    u32x4 pa0v = {x0, x1, y0, y1};
    u32x4 pa1v = {x2, x3, y2, y3};
    s16x8 pa0 = __builtin_bit_cast(s16x8, pa0v);
    s16x8 pa1 = __builtin_bit_cast(s16x8, pa1v);
    __builtin_amdgcn_s_setprio(1);
#pragma unroll
    for (int ks = 0; ks < 2; ++ks) {
      s16x8 pa = ks ? pa1 : pa0;
      const int tb = (ks * 32 + hi * 16) ^ vswz;
      const char* vbase = (const char*)Vs[cur] + q32 * 64 + tb;
      s16x8 vb;
      vb = *(const s16x8*)(vbase + 0 * 2048);
      o0 = __builtin_amdgcn_mfma_f32_32x32x16_bf16(pa, vb, o0, 0, 0, 0);
      vb = *(const s16x8*)(vbase + 1 * 2048);
      o1 = __builtin_amdgcn_mfma_f32_32x32x16_bf16(pa, vb, o1, 0, 0, 0);
      vb = *(const s16x8*)(vbase + 2 * 2048);
      o2 = __builtin_amdgcn_mfma_f32_32x32x16_bf16(pa, vb, o2, 0, 0, 0);
      vb = *(const s16x8*)(vbase + 3 * 2048);
      o3 = __builtin_amdgcn_mfma_f32_32x32x16_bf16(pa, vb, o3, 0, 0, 0);
    }
    __builtin_amdgcn_s_setprio(0);
    __syncthreads();
    cur ^= 1;
  }
  lsum += __shfl_xor(lsum, 32, 64);
  {
    int qrow = q0 + q32;
    if (hi == 0 && qrow < S) lbufz[(size_t)qrow * 12 + h] = lsum;
  }
#pragma unroll
  for (int r = 0; r < 16; ++r) {
    int qrow = q0 + (r & 3) + 8 * (r >> 2) + 4 * hi;
    if (qrow < S) {
      float* orow = obufz + (size_t)qrow * 1536 + h * 128 + q32;
      orow[0] = o0[r]; orow[32] = o1[r]; orow[64] = o2[r]; orow[96] = o3[r];
    }
  }
#undef STAGE
}

extern "C" void kernel_launch(void* const* d_in, const int* in_sizes, int n_in,
                              void* d_out, int out_size, void* d_ws, size_t ws_size,
                              hipStream_t stream) {
  const float* x = (const float*)d_in[0];
  const float* freqs = (const float*)d_in[1];
  const float* g_kmean = (const float*)d_in[2];
  const float* g_kv = (const float*)d_in[3];
  const float* Wq = (const float*)d_in[4];  const float* bq = (const float*)d_in[5];
  const float* Wk = (const float*)d_in[6];  const float* bk = (const float*)d_in[7];
  const float* Wv = (const float*)d_in[8];  const float* bv = (const float*)d_in[9];
  const float* Wo = (const float*)d_in[10]; const float* bo = (const float*)d_in[11];
  const float* gq = (const float*)d_in[12]; const float* gk = (const float*)d_in[13];
  const float* Wlin = (const float*)d_in[14]; const float* blin = (const float*)d_in[15];
  const int* hgp = (const int*)d_in[17];
  const int* wgp = (const int*)d_in[18];

  const int S = in_sizes[0] / 1536;

  char* ws = (char*)d_ws;
  const size_t SZ = (size_t)S * 1536 * 2;        // bf16 (S,1536)
  const size_t OSZ = (size_t)S * 1536 * 4;       // f32 (S,1536) partial
  const size_t WSZ = (size_t)1536 * 1536 * 2;    // bf16 1536^2
  const size_t QKVSZ = (size_t)S * 4608 * 2;     // bf16 (S,4608)
  const size_t G2SZ = (size_t)12 * 128 * 128 * 2;
  size_t o_xbf = 0;
  size_t o_wqkv = o_xbf + SZ;
  size_t o_wo = o_wqkv + 3 * WSZ;                // contiguous after wqkv (cast_weights4 relies on this)
  size_t o_g2 = o_wo + WSZ;
  size_t o_qkv = o_g2 + G2SZ;
  size_t o_rk = o_qkv + QKVSZ;
  size_t o_vt = o_rk + SZ;
  size_t o_z = o_vt + SZ;
  size_t o_bqkv = o_z + (size_t)S * 12 * 4;
  size_t o_o1 = o_bqkv + 4608 * 4;

  // choose split depth: prefer 3 (fits per R10's nsplit-4 run), fall back to 2
  int nsplit = 3;
  if (ws_size < o_o1 + (size_t)2 * OSZ + (size_t)3 * S * 12 * 4) nsplit = 2;
  size_t o_l = o_o1 + (size_t)(nsplit - 1) * OSZ;
  size_t need = o_l + (size_t)nsplit * S * 12 * 4;
  if (ws_size < need) return;

  unsigned short* xbf = (unsigned short*)(ws + o_xbf);
  unsigned short* wqkv = (unsigned short*)(ws + o_wqkv);
  unsigned short* wob = (unsigned short*)(ws + o_wo);
  unsigned short* g2c = (unsigned short*)(ws + o_g2);
  unsigned short* qkv = (unsigned short*)(ws + o_qkv);
  unsigned short* rkb = (unsigned short*)(ws + o_rk);
  unsigned short* vtb = (unsigned short*)(ws + o_vt);
  float* zbuf = (float*)(ws + o_z);
  float* bqkv = (float*)(ws + o_bqkv);
  unsigned short* rqb = xbf;
  float* o0buf = (float*)(ws + o_qkv);
  float* o1buf = (float*)(ws + o_o1);
  float* lbuf = (float*)(ws + o_l);
  unsigned short* ybf = (unsigned short*)(ws + o_qkv + OSZ);

  // 1) casts (x separate; 4 weights fused into one launch -> contiguous wqkv|wob)
  {
    int n4 = (S * 1536) / 4;
    cast_f32_bf16_x4<<<(n4 + 255) / 256, 256, 0, stream>>>(x, xbf, n4);
    int per4 = (1536 * 1536) / 4;
    cast_weights4<<<(4 * per4 + 255) / 256, 256, 0, stream>>>(Wq, Wk, Wv, Wo, wqkv, per4);
  }
  hipMemcpyAsync(bqkv, bq, 1536 * 4, hipMemcpyDeviceToDevice, stream);
  hipMemcpyAsync(bqkv + 1536, bk, 1536 * 4, hipMemcpyDeviceToDevice, stream);
  hipMemcpyAsync(bqkv + 3072, bv, 1536 * 4, hipMemcpyDeviceToDevice, stream);

  // 2) compact block-diagonal G2c
  g2fill_kernel<<<dim3(12, 128), 128, 0, stream>>>(g_kv, Wlin, g2c);

  // 3) merged QKV projection (proven 128^2 GEMM): qkv[S][4608]
  {
    dim3 ggrid((S + 127) / 128, 36);
    gemm_bt<0, 2><<<ggrid, 256, 0, stream>>>(xbf, wqkv, bqkv, qkv, S, 4608, 1536, 1536, 1536,
                                             nullptr, nullptr, nullptr, nullptr);
  }

  // 4) fused RMS + RoPE for q and k (+z for q)
  rms_rope_kernel<<<dim3(S, 2), 256, 0, stream>>>(qkv, freqs, gq, gk, g_kmean,
                                                  rqb, rkb, zbuf, S, hgp, wgp);

  // 5) V transpose
  vtrans_kernel<<<dim3((S + 63) / 64, 24), 256, 0, stream>>>(qkv + 3072, vtb, S, 4608);

  // 6) attention, KV-split x nsplit (R9-verbatim kernel)
  {
    int nqb = (S + 127) / 128;
    attn_kernel<<<dim3(nqb * 12 * nsplit), 256, 0, stream>>>(rqb, rkb, vtb,
                                                             o0buf, o1buf, lbuf, S, nqb, nsplit);
  }

  // 7) xg merge (block-diag, K=128, compile-time NSPLIT) -> ybf ; 8) out GEMM
  {
    dim3 ggrid((S + 127) / 128, 12);
    if (nsplit == 3) {
      gemm_bt<3, 3><<<ggrid, 256, 0, stream>>>(rqb, g2c, blin, ybf, S, 1536, 128, 1536, 128,
                                               o0buf, zbuf, o1buf, lbuf);
    } else {
      gemm_bt<3, 2><<<ggrid, 256, 0, stream>>>(rqb, g2c, blin, ybf, S, 1536, 128, 1536, 128,
                                               o0buf, zbuf, o1buf, lbuf);
    }
    gemm_bt<1, 2><<<ggrid, 256, 0, stream>>>(ybf, wob, bo, (float*)d_out, S, 1536, 1536, 1536, 1536,
                                             nullptr, nullptr, nullptr, nullptr);
  }
}

// Round 16
// 405.223 us; speedup vs baseline: 1.1923x; 1.0077x over previous
//
#include <hip/hip_runtime.h>

typedef short s16x8 __attribute__((ext_vector_type(8)));
typedef float f32x4 __attribute__((ext_vector_type(4)));
typedef float f32x16 __attribute__((ext_vector_type(16)));
typedef unsigned short u16x4 __attribute__((ext_vector_type(4)));
typedef unsigned int u32x4 __attribute__((ext_vector_type(4)));

#define QSCALE (0.08838834764831845f * 1.4426950408889634f)

__device__ __forceinline__ unsigned short f2bf(float f) {
  unsigned int u = __float_as_uint(f);
  u += 0x7fffu + ((u >> 16) & 1u);
  return (unsigned short)(u >> 16);
}
__device__ __forceinline__ float bf2f(unsigned short h) {
  return __uint_as_float((unsigned int)h << 16);
}
__device__ __forceinline__ float fast_exp2(float x) {
  float r;
  asm("v_exp_f32 %0, %1" : "=v"(r) : "v"(x));
  return r;
}

__device__ __forceinline__ void gload16(const void* gp, void* lp) {
  __builtin_amdgcn_global_load_lds(
      (const __attribute__((address_space(1))) void*)gp,
      (__attribute__((address_space(3))) void*)lp,
      16, 0, 0);
}

// ---------------- cast f32 -> bf16, 4 at a time ----------------
__global__ void cast_f32_bf16_x4(const float* __restrict__ in,
                                 unsigned short* __restrict__ out, int n4) {
  int i = blockIdx.x * 256 + threadIdx.x;
  if (i >= n4) return;
  f32x4 v = *((const f32x4*)in + i);
  u16x4 o;
  o[0] = f2bf(v[0]); o[1] = f2bf(v[1]); o[2] = f2bf(v[2]); o[3] = f2bf(v[3]);
  *((u16x4*)out + i) = o;
}

// ---------------- fused weight cast: Wq|Wk|Wv|Wo -> contiguous bf16 dst ----------------
__global__ void cast_weights4(const float* __restrict__ Wq, const float* __restrict__ Wk,
                              const float* __restrict__ Wv, const float* __restrict__ Wo,
                              unsigned short* __restrict__ dst, int per4) {
  int i = blockIdx.x * 256 + threadIdx.x;
  if (i >= 4 * per4) return;
  int m = i / per4;
  int off = i - m * per4;
  const float* src = (m == 0) ? Wq : (m == 1) ? Wk : (m == 2) ? Wv : Wo;
  f32x4 v = *((const f32x4*)src + off);
  u16x4 o;
  o[0] = f2bf(v[0]); o[1] = f2bf(v[1]); o[2] = f2bf(v[2]); o[3] = f2bf(v[3]);
  *((u16x4*)dst + i) = o;
}

// ---------------- compact G2c[h*128+m][d] = (1/QSCALE) * sum_j g_kv[h][d][j]*Wlin[m][j] ----
__global__ void g2fill_kernel(const float* __restrict__ g_kv,
                              const float* __restrict__ Wlin,
                              unsigned short* __restrict__ G2c) {
  int h = blockIdx.x, m = blockIdx.y, d = threadIdx.x;
  const float* gk = g_kv + ((size_t)h * 128 + d) * 128;
  const float* wl = Wlin + (size_t)m * 128;
  float s = 0.f;
  for (int j = 0; j < 128; ++j) s += gk[j] * wl[j];
  G2c[((size_t)h * 128 + m) * 128 + d] = f2bf(s * (1.0f / QSCALE));
}

// ---------------- GEMM: C[M,N] = A[M,K] @ B[N,K]^T (+ epilogue) ----------------
// MODE 0: bf16 out, +bias[cc]
// MODE 1: f32 out, +bias[cc]
// MODE 3: block-diag per-head (A col offset nt*128, compact B), NSPLIT-way merge epilogue
template <int MODE, int NSPLIT>
__global__ __launch_bounds__(256) void gemm_bt(
    const unsigned short* __restrict__ A, const unsigned short* __restrict__ B,
    const float* __restrict__ bias, void* __restrict__ Cout,
    int M, int N, int K, int lda, int ldb,
    const float* __restrict__ o0buf, const float* __restrict__ zbuf,
    const float* __restrict__ o1buf, const float* __restrict__ lbuf) {
  __shared__ __align__(16) unsigned short Asm_[128 * 64];
  __shared__ __align__(16) unsigned short Bsm_[128 * 64];
  const int tid = threadIdx.x;
  const int wid = tid >> 6, lane = tid & 63;
  const int mt = blockIdx.x, nt = blockIdx.y;
  const int wr = wid >> 1, wc = wid & 1;
  const int acol = (MODE == 3) ? nt * 128 : 0;
  f32x4 acc[4][4] = {};

  const int st_srccol = ((((lane & 7) << 4) ^ ((lane >> 3) << 4)) >> 1);  // elements
  const int st_rowoff = (lane >> 3);

  for (int k0 = 0; k0 < K; k0 += 64) {
    __syncthreads();
#pragma unroll
    for (int r = 0; r < 4; ++r) {
      int c = wid * 4 + r;
      int lrow = c * 8 + st_rowoff;
      int arow = mt * 128 + lrow; if (arow > M - 1) arow = M - 1;
      gload16(A + (size_t)arow * lda + acol + k0 + st_srccol,
              (char*)Asm_ + c * 1024 + lane * 16);
      int brow = nt * 128 + lrow;
      gload16(B + (size_t)brow * ldb + k0 + st_srccol,
              (char*)Bsm_ + c * 1024 + lane * 16);
    }
    __syncthreads();
#pragma unroll
    for (int kk = 0; kk < 2; ++kk) {
      int cb = (kk * 64 + ((lane >> 4) << 4)) ^ ((lane & 7) << 4);
      s16x8 af[4], bfr[4];
#pragma unroll
      for (int m = 0; m < 4; ++m)
        af[m] = *(const s16x8*)((const char*)Asm_ + (wr * 64 + m * 16 + (lane & 15)) * 128 + cb);
#pragma unroll
      for (int n = 0; n < 4; ++n)
        bfr[n] = *(const s16x8*)((const char*)Bsm_ + (wc * 64 + n * 16 + (lane & 15)) * 128 + cb);
#pragma unroll
      for (int m = 0; m < 4; ++m)
#pragma unroll
        for (int n = 0; n < 4; ++n)
          acc[m][n] = __builtin_amdgcn_mfma_f32_16x16x32_bf16(af[m], bfr[n], acc[m][n], 0, 0, 0);
    }
  }
  const int rb = mt * 128 + wr * 64, cbse = nt * 128 + wc * 64;
#pragma unroll
  for (int m = 0; m < 4; ++m) {
#pragma unroll
    for (int n = 0; n < 4; ++n) {
#pragma unroll
      for (int rg = 0; rg < 4; ++rg) {
        int rr = rb + m * 16 + ((lane >> 4) << 2) + rg;
        int cc = cbse + n * 16 + (lane & 15);
        if (rr < M) {
          float v = acc[m][n][rg];
          if (MODE == 0) {
            v += bias[cc];
            ((unsigned short*)Cout)[(size_t)rr * N + cc] = f2bf(v);
          } else if (MODE == 1) {
            v += bias[cc];
            ((float*)Cout)[(size_t)rr * N + cc] = v;
          } else {
            int hd = cc >> 7;
            float lsum = lbuf[(size_t)rr * 12 + hd];
            float osum = o0buf[(size_t)rr * N + cc];
#pragma unroll
            for (int s = 1; s < NSPLIT; ++s) {
              lsum += lbuf[((size_t)s * M + rr) * 12 + hd];
              osum += o1buf[(size_t)(s - 1) * M * 1536 + (size_t)rr * N + cc];
            }
            v = v * zbuf[(size_t)rr * 12 + hd] + osum * (1.0f / lsum) + bias[cc & 127];
            ((unsigned short*)Cout)[(size_t)rr * N + cc] = f2bf(v);
          }
        }
      }
    }
  }
}

// ---------------- fused RMS + RoPE for q (blockIdx.y==0) and k (blockIdx.y==1) -----------
__global__ __launch_bounds__(256) void rms_rope_kernel(
    const unsigned short* __restrict__ qkv, const float* __restrict__ freqs,
    const float* __restrict__ gq, const float* __restrict__ gk,
    const float* __restrict__ g_kmean,
    unsigned short* __restrict__ rqb, unsigned short* __restrict__ rkb,
    float* __restrict__ zbuf, int S,
    const int* __restrict__ hgp, const int* __restrict__ wgp) {
  const int s = blockIdx.x;
  const int isk = blockIdx.y;
  const unsigned short* row = qkv + (size_t)s * 4608 + (isk ? 1536 : 0);
  const float* g = isk ? gk : gq;
  unsigned short* outr = isk ? rkb : rqb;
  float* zout = isk ? nullptr : zbuf;
  const float oscale = isk ? 1.0f : QSCALE;
  const int tid = threadIdx.x;
  const int lane = tid & 63, wid = tid >> 6;
  unsigned int pv0, pv1, pv2;
  float ssq = 0.f;
  {
    pv0 = *(const unsigned int*)(row + 2 * (tid));
    pv1 = *(const unsigned int*)(row + 2 * (tid + 256));
    pv2 = *(const unsigned int*)(row + 2 * (tid + 512));
    float a0 = bf2f((unsigned short)(pv0 & 0xffffu)), b0 = bf2f((unsigned short)(pv0 >> 16));
    float a1 = bf2f((unsigned short)(pv1 & 0xffffu)), b1 = bf2f((unsigned short)(pv1 >> 16));
    float a2 = bf2f((unsigned short)(pv2 & 0xffffu)), b2 = bf2f((unsigned short)(pv2 >> 16));
    ssq = a0 * a0 + b0 * b0 + a1 * a1 + b1 * b1 + a2 * a2 + b2 * b2;
  }
#pragma unroll
  for (int m = 1; m < 64; m <<= 1) ssq += __shfl_xor(ssq, m, 64);
  __shared__ float wpart[4];
  if (lane == 0) wpart[wid] = ssq;
  __syncthreads();
  float tot = wpart[0] + wpart[1] + wpart[2] + wpart[3];
  float rms = rsqrtf(tot * (1.0f / 1536.0f) + 1e-6f);
  const int Wg = *wgp;
  const int HWg = (*hgp) * Wg;
  int fi = s / HWg; int rem = s - fi * HWg;
  int hi = rem / Wg; int wi = rem - hi * Wg;
  unsigned int pvs[3] = {pv0, pv1, pv2};
#pragma unroll
  for (int rd = 0; rd < 3; ++rd) {
    int p = tid + rd * 256;
    int c = p & 63;
    int fidx = (c < 22) ? fi : ((c < 43) ? hi : wi);
    float cr = freqs[fidx * 128 + 2 * c];
    float ci = freqs[fidx * 128 + 2 * c + 1];
    float xr = bf2f((unsigned short)(pvs[rd] & 0xffffu)) * rms * g[2 * p];
    float xi = bf2f((unsigned short)(pvs[rd] >> 16)) * rms * g[2 * p + 1];
    float yr = (xr * cr - xi * ci) * oscale;
    float yi = (xr * ci + xi * cr) * oscale;
    unsigned int ow = (unsigned int)f2bf(yr) | ((unsigned int)f2bf(yi) << 16);
    *(unsigned int*)(outr + (size_t)s * 1536 + 2 * p) = ow;
    if (zout != nullptr) {
      int head = p >> 6;
      float part = fmaxf(xr, 0.f) * g_kmean[head * 128 + 2 * c] +
                   fmaxf(xi, 0.f) * g_kmean[head * 128 + 2 * c + 1];
#pragma unroll
      for (int m = 1; m < 64; m <<= 1) part += __shfl_xor(part, m, 64);
      if (lane == 0) zout[(size_t)s * 12 + head] = 1.0f / (part + 1e-6f);
    }
  }
}

// ---------------- V transpose: vpre (S, ld cols used 64) bf16 -> vt (1536, S) bf16 ----------------
__global__ __launch_bounds__(256) void vtrans_kernel(const unsigned short* __restrict__ vpre,
                                                     unsigned short* __restrict__ vt, int S, int ld) {
  __shared__ unsigned short tile[64][66];
  int t0 = blockIdx.x * 64, c0 = blockIdx.y * 64;
  int tid = threadIdx.x;
#pragma unroll
  for (int rep = 0; rep < 16; ++rep) {
    int lin = rep * 256 + tid;
    int i = lin >> 6, j = lin & 63;
    int t = t0 + i; if (t > S - 1) t = S - 1;
    tile[i][j] = vpre[(size_t)t * ld + c0 + j];
  }
  __syncthreads();
#pragma unroll
  for (int rep = 0; rep < 16; ++rep) {
    int lin = rep * 256 + tid;
    int j = lin >> 6, i = lin & 63;
    int t = t0 + i;
    if (t < S) vt[(size_t)(c0 + j) * S + t] = tile[i][j];
  }
}

// ---------------- Flash attention, 32x32 MFMA, in-register P (permlane32_swap), ----------
// ---------------- no-max softmax, KV-split x nsplit, KVBLK=32 --------------------------
// R15 structure; ONLY change: conflict-free LDS for K (4-bit key) and V ([32 row][256B]
// quadrant layout, 4-bit key) -> 2-way max bank aliasing (free per m136).
__global__ __launch_bounds__(256, 3) void attn_kernel(
    const unsigned short* __restrict__ rq, const unsigned short* __restrict__ rk,
    const unsigned short* __restrict__ vt, float* __restrict__ o0buf,
    float* __restrict__ o1buf, float* __restrict__ lbuf, int S, int nqb, int nsplit) {
  __shared__ __align__(16) unsigned short Ks[2][32 * 128];  // [tok][256B], key (tok&15)<<4
  __shared__ __align__(16) unsigned short Vs[2][32 * 128];  // [d&31][256B: (d>>5)*64+2*tok], key (row&15)<<4
  const int tid = threadIdx.x, wid = tid >> 6, lane = tid & 63;
  const int q32 = lane & 31, hi = lane >> 5;

  const int total = nqb * 12 * nsplit;
  int lg = blockIdx.x;
  if ((total & 7) == 0) lg = (lg & 7) * (total >> 3) + (lg >> 3);
  const int z = lg / (nqb * 12);
  int rem = lg - z * nqb * 12;
  const int h = rem / nqb;
  const int qb = rem - h * nqb;
  const int q0 = qb * 128 + wid * 32;

  const int seg = (((S + nsplit - 1) / nsplit) + 31) & ~31;
  const int tbeg = z * seg;
  const int tend = (tbeg + seg < S) ? (tbeg + seg) : S;
  float* obufz = (z == 0) ? o0buf : (o1buf + (size_t)(z - 1) * S * 1536);
  float* lbufz = lbuf + (size_t)z * S * 12;

  s16x8 qf[8];
  {
    int qrow = q0 + q32; if (qrow > S - 1) qrow = S - 1;
    const unsigned short* qp = rq + (size_t)qrow * 1536 + h * 128 + hi * 8;
#pragma unroll
    for (int dblk = 0; dblk < 8; ++dblk) qf[dblk] = *(const s16x8*)(qp + dblk * 16);
  }
  f32x16 o0 = {}, o1 = {}, o2 = {}, o3 = {};
  float lsum = 0.f;

  const int st_row0 = tid >> 4;           // + 16*r
  const int st_off = (tid & 15) * 16;     // byte offset within 256B row (dest)
  const int kswz = (q32 & 15) << 4;       // read-side K key
  const int vswz = (q32 & 15) << 4;       // read-side V key

#define STAGE(buf, t0s)                                                            \
  {                                                                                \
    _Pragma("unroll") for (int r = 0; r < 2; ++r) {                                \
      int row = st_row0 + 16 * r;                                                  \
      int key = (row & 15) << 4;                                                   \
      /* K: row = token; logical byte L = st_off ^ key -> dim halfword L>>1 */     \
      int kL = st_off ^ key;                                                       \
      int trow = (t0s) + row; if (trow > S - 1) trow = S - 1;                      \
      gload16(rk + (size_t)trow * 1536 + h * 128 + (kL >> 1),                      \
              (char*)Ks[buf] + r * 4096 + tid * 16);                               \
      /* V: row = d&31; logical L: quadrant L>>6 -> d+=32*, tok = (L&63)>>1 */     \
      int vL = st_off ^ key;                                                       \
      int vd = row + 32 * (vL >> 6);                                               \
      int vtok = (t0s) + ((vL & 63) >> 1); if (vtok > S - 8) vtok = S - 8;         \
      gload16(vt + (size_t)(h * 128 + vd) * S + vtok,                              \
              (char*)Vs[buf] + r * 4096 + tid * 16);                               \
    }                                                                              \
  }

  STAGE(0, tbeg);
  __syncthreads();
  int cur = 0;
  for (int t0 = tbeg; t0 < tend; t0 += 32) {
    if (t0 + 32 < tend) STAGE(cur ^ 1, t0 + 32);
    f32x16 sc = {};
    __builtin_amdgcn_s_setprio(1);
#pragma unroll
    for (int dblk = 0; dblk < 8; ++dblk) {
      s16x8 kfr = *(const s16x8*)((const char*)Ks[cur] + q32 * 256 +
                                  ((dblk * 32 + hi * 16) ^ kswz));
      sc = __builtin_amdgcn_mfma_f32_32x32x16_bf16(kfr, qf[dblk], sc, 0, 0, 0);
    }
    __builtin_amdgcn_s_setprio(0);
    const bool full = (t0 + 32 <= tend);
    unsigned int pk[8];
    float rs = 0.f;
#pragma unroll
    for (int j = 0; j < 8; ++j) {
      float p0, p1;
      if (full) {
        p0 = fast_exp2(sc[2 * j]);
        p1 = fast_exp2(sc[2 * j + 1]);
      } else {
        int r0 = 2 * j;
        int tk0 = t0 + (r0 & 3) + 8 * (r0 >> 2) + 4 * hi;
        p0 = (tk0 < tend) ? fast_exp2(sc[2 * j]) : 0.f;
        p1 = (tk0 + 1 < tend) ? fast_exp2(sc[2 * j + 1]) : 0.f;
      }
      unsigned int u0 = __float_as_uint(p0) & 0xffff0000u;
      unsigned int u1 = __float_as_uint(p1) & 0xffff0000u;
      rs += __uint_as_float(u0) + __uint_as_float(u1);
      pk[j] = (u0 >> 16) | u1;
    }
    lsum += rs;
    unsigned int x0 = pk[0], y0 = pk[2], x1 = pk[1], y1 = pk[3];
    asm("v_permlane32_swap_b32 %0, %1" : "+v"(x0), "+v"(y0));
    asm("v_permlane32_swap_b32 %0, %1" : "+v"(x1), "+v"(y1));
    unsigned int x2 = pk[4], y2 = pk[6], x3 = pk[5], y3 = pk[7];
    asm("v_permlane32_swap_b32 %0, %1" : "+v"(x2), "+v"(y2));
    asm("v_permlane32_swap_b32 %0, %1" : "+v"(x3), "+v"(y3));
    u32x4 pa0v = {x0, x1, y0, y1};
    u32x4 pa1v = {x2, x3, y2, y3};
    s16x8 pa0 = __builtin_bit_cast(s16x8, pa0v);
    s16x8 pa1 = __builtin_bit_cast(s16x8, pa1v);
    __builtin_amdgcn_s_setprio(1);
    {
      const char* vrowb = (const char*)Vs[cur] + q32 * 256;
#pragma unroll
      for (int ks = 0; ks < 2; ++ks) {
        s16x8 pa = ks ? pa1 : pa0;
        s16x8 vb;
        vb = *(const s16x8*)(vrowb + ((0 * 64 + ks * 32 + hi * 16) ^ vswz));
        o0 = __builtin_amdgcn_mfma_f32_32x32x16_bf16(pa, vb, o0, 0, 0, 0);
        vb = *(const s16x8*)(vrowb + ((1 * 64 + ks * 32 + hi * 16) ^ vswz));
        o1 = __builtin_amdgcn_mfma_f32_32x32x16_bf16(pa, vb, o1, 0, 0, 0);
        vb = *(const s16x8*)(vrowb + ((2 * 64 + ks * 32 + hi * 16) ^ vswz));
        o2 = __builtin_amdgcn_mfma_f32_32x32x16_bf16(pa, vb, o2, 0, 0, 0);
        vb = *(const s16x8*)(vrowb + ((3 * 64 + ks * 32 + hi * 16) ^ vswz));
        o3 = __builtin_amdgcn_mfma_f32_32x32x16_bf16(pa, vb, o3, 0, 0, 0);
      }
    }
    __builtin_amdgcn_s_setprio(0);
    __syncthreads();
    cur ^= 1;
  }
  lsum += __shfl_xor(lsum, 32, 64);
  {
    int qrow = q0 + q32;
    if (hi == 0 && qrow < S) lbufz[(size_t)qrow * 12 + h] = lsum;
  }
#pragma unroll
  for (int r = 0; r < 16; ++r) {
    int qrow = q0 + (r & 3) + 8 * (r >> 2) + 4 * hi;
    if (qrow < S) {
      float* orow = obufz + (size_t)qrow * 1536 + h * 128 + q32;
      orow[0] = o0[r]; orow[32] = o1[r]; orow[64] = o2[r]; orow[96] = o3[r];
    }
  }
#undef STAGE
}

extern "C" void kernel_launch(void* const* d_in, const int* in_sizes, int n_in,
                              void* d_out, int out_size, void* d_ws, size_t ws_size,
                              hipStream_t stream) {
  const float* x = (const float*)d_in[0];
  const float* freqs = (const float*)d_in[1];
  const float* g_kmean = (const float*)d_in[2];
  const float* g_kv = (const float*)d_in[3];
  const float* Wq = (const float*)d_in[4];  const float* bq = (const float*)d_in[5];
  const float* Wk = (const float*)d_in[6];  const float* bk = (const float*)d_in[7];
  const float* Wv = (const float*)d_in[8];  const float* bv = (const float*)d_in[9];
  const float* Wo = (const float*)d_in[10]; const float* bo = (const float*)d_in[11];
  const float* gq = (const float*)d_in[12]; const float* gk = (const float*)d_in[13];
  const float* Wlin = (const float*)d_in[14]; const float* blin = (const float*)d_in[15];
  const int* hgp = (const int*)d_in[17];
  const int* wgp = (const int*)d_in[18];

  const int S = in_sizes[0] / 1536;

  char* ws = (char*)d_ws;
  const size_t SZ = (size_t)S * 1536 * 2;        // bf16 (S,1536)
  const size_t OSZ = (size_t)S * 1536 * 4;       // f32 (S,1536) partial
  const size_t WSZ = (size_t)1536 * 1536 * 2;    // bf16 1536^2
  const size_t QKVSZ = (size_t)S * 4608 * 2;     // bf16 (S,4608)
  const size_t G2SZ = (size_t)12 * 128 * 128 * 2;
  size_t o_xbf = 0;
  size_t o_wqkv = o_xbf + SZ;
  size_t o_wo = o_wqkv + 3 * WSZ;                // contiguous after wqkv (cast_weights4 relies on this)
  size_t o_g2 = o_wo + WSZ;
  size_t o_qkv = o_g2 + G2SZ;
  size_t o_rk = o_qkv + QKVSZ;
  size_t o_vt = o_rk + SZ;
  size_t o_z = o_vt + SZ;
  size_t o_bqkv = o_z + (size_t)S * 12 * 4;
  size_t o_o1 = o_bqkv + 4608 * 4;

  // choose split depth: prefer 3, fall back to 2
  int nsplit = 3;
  if (ws_size < o_o1 + (size_t)2 * OSZ + (size_t)3 * S * 12 * 4) nsplit = 2;
  size_t o_l = o_o1 + (size_t)(nsplit - 1) * OSZ;
  size_t need = o_l + (size_t)nsplit * S * 12 * 4;
  if (ws_size < need) return;

  unsigned short* xbf = (unsigned short*)(ws + o_xbf);
  unsigned short* wqkv = (unsigned short*)(ws + o_wqkv);
  unsigned short* wob = (unsigned short*)(ws + o_wo);
  unsigned short* g2c = (unsigned short*)(ws + o_g2);
  unsigned short* qkv = (unsigned short*)(ws + o_qkv);
  unsigned short* rkb = (unsigned short*)(ws + o_rk);
  unsigned short* vtb = (unsigned short*)(ws + o_vt);
  float* zbuf = (float*)(ws + o_z);
  float* bqkv = (float*)(ws + o_bqkv);
  unsigned short* rqb = xbf;
  float* o0buf = (float*)(ws + o_qkv);
  float* o1buf = (float*)(ws + o_o1);
  float* lbuf = (float*)(ws + o_l);
  unsigned short* ybf = (unsigned short*)(ws + o_qkv + OSZ);

  // 1) casts
  {
    int n4 = (S * 1536) / 4;
    cast_f32_bf16_x4<<<(n4 + 255) / 256, 256, 0, stream>>>(x, xbf, n4);
    int per4 = (1536 * 1536) / 4;
    cast_weights4<<<(4 * per4 + 255) / 256, 256, 0, stream>>>(Wq, Wk, Wv, Wo, wqkv, per4);
  }
  hipMemcpyAsync(bqkv, bq, 1536 * 4, hipMemcpyDeviceToDevice, stream);
  hipMemcpyAsync(bqkv + 1536, bk, 1536 * 4, hipMemcpyDeviceToDevice, stream);
  hipMemcpyAsync(bqkv + 3072, bv, 1536 * 4, hipMemcpyDeviceToDevice, stream);

  // 2) compact block-diagonal G2c
  g2fill_kernel<<<dim3(12, 128), 128, 0, stream>>>(g_kv, Wlin, g2c);

  // 3) merged QKV projection (proven 128^2 GEMM): qkv[S][4608]
  {
    dim3 ggrid((S + 127) / 128, 36);
    gemm_bt<0, 2><<<ggrid, 256, 0, stream>>>(xbf, wqkv, bqkv, qkv, S, 4608, 1536, 1536, 1536,
                                             nullptr, nullptr, nullptr, nullptr);
  }

  // 4) fused RMS + RoPE for q and k (+z for q)
  rms_rope_kernel<<<dim3(S, 2), 256, 0, stream>>>(qkv, freqs, gq, gk, g_kmean,
                                                  rqb, rkb, zbuf, S, hgp, wgp);

  // 5) V transpose
  vtrans_kernel<<<dim3((S + 63) / 64, 24), 256, 0, stream>>>(qkv + 3072, vtb, S, 4608);

  // 6) attention, KV-split x nsplit (conflict-free LDS keys)
  {
    int nqb = (S + 127) / 128;
    attn_kernel<<<dim3(nqb * 12 * nsplit), 256, 0, stream>>>(rqb, rkb, vtb,
                                                             o0buf, o1buf, lbuf, S, nqb, nsplit);
  }

  // 7) xg merge (block-diag, K=128, compile-time NSPLIT) -> ybf ; 8) out GEMM
  {
    dim3 ggrid((S + 127) / 128, 12);
    if (nsplit == 3) {
      gemm_bt<3, 3><<<ggrid, 256, 0, stream>>>(rqb, g2c, blin, ybf, S, 1536, 128, 1536, 128,
                                               o0buf, zbuf, o1buf, lbuf);
    } else {
      gemm_bt<3, 2><<<ggrid, 256, 0, stream>>>(rqb, g2c, blin, ybf, S, 1536, 128, 1536, 128,
                                               o0buf, zbuf, o1buf, lbuf);
    }
    gemm_bt<1, 2><<<ggrid, 256, 0, stream>>>(ybf, wob, bo, (float*)d_out, S, 1536, 1536, 1536, 1536,
                                             nullptr, nullptr, nullptr, nullptr);
  }
}

// Round 17
// 398.814 us; speedup vs baseline: 1.2115x; 1.0161x over previous
//
#include <hip/hip_runtime.h>

typedef short s16x8 __attribute__((ext_vector_type(8)));
typedef float f32x4 __attribute__((ext_vector_type(4)));
typedef float f32x16 __attribute__((ext_vector_type(16)));
typedef unsigned short u16x4 __attribute__((ext_vector_type(4)));
typedef unsigned int u32x4 __attribute__((ext_vector_type(4)));

#define QSCALE (0.08838834764831845f * 1.4426950408889634f)

__device__ __forceinline__ unsigned short f2bf(float f) {
  unsigned int u = __float_as_uint(f);
  u += 0x7fffu + ((u >> 16) & 1u);
  return (unsigned short)(u >> 16);
}
__device__ __forceinline__ float bf2f(unsigned short h) {
  return __uint_as_float((unsigned int)h << 16);
}
__device__ __forceinline__ float fast_exp2(float x) {
  float r;
  asm("v_exp_f32 %0, %1" : "=v"(r) : "v"(x));
  return r;
}

__device__ __forceinline__ void gload16(const void* gp, void* lp) {
  __builtin_amdgcn_global_load_lds(
      (const __attribute__((address_space(1))) void*)gp,
      (__attribute__((address_space(3))) void*)lp,
      16, 0, 0);
}

// ---------------- cast f32 -> bf16, 4 at a time ----------------
__global__ void cast_f32_bf16_x4(const float* __restrict__ in,
                                 unsigned short* __restrict__ out, int n4) {
  int i = blockIdx.x * 256 + threadIdx.x;
  if (i >= n4) return;
  f32x4 v = *((const f32x4*)in + i);
  u16x4 o;
  o[0] = f2bf(v[0]); o[1] = f2bf(v[1]); o[2] = f2bf(v[2]); o[3] = f2bf(v[3]);
  *((u16x4*)out + i) = o;
}

// ---------------- fused weight cast: Wq|Wk|Wv|Wo -> contiguous bf16 dst ----------------
__global__ void cast_weights4(const float* __restrict__ Wq, const float* __restrict__ Wk,
                              const float* __restrict__ Wv, const float* __restrict__ Wo,
                              unsigned short* __restrict__ dst, int per4) {
  int i = blockIdx.x * 256 + threadIdx.x;
  if (i >= 4 * per4) return;
  int m = i / per4;
  int off = i - m * per4;
  const float* src = (m == 0) ? Wq : (m == 1) ? Wk : (m == 2) ? Wv : Wo;
  f32x4 v = *((const f32x4*)src + off);
  u16x4 o;
  o[0] = f2bf(v[0]); o[1] = f2bf(v[1]); o[2] = f2bf(v[2]); o[3] = f2bf(v[3]);
  *((u16x4*)dst + i) = o;
}

// ---------------- compact G2c[h*128+m][d] = (1/QSCALE) * sum_j g_kv[h][d][j]*Wlin[m][j] ----
__global__ void g2fill_kernel(const float* __restrict__ g_kv,
                              const float* __restrict__ Wlin,
                              unsigned short* __restrict__ G2c) {
  int h = blockIdx.x, m = blockIdx.y, d = threadIdx.x;
  const float* gk = g_kv + ((size_t)h * 128 + d) * 128;
  const float* wl = Wlin + (size_t)m * 128;
  float s = 0.f;
  for (int j = 0; j < 128; ++j) s += gk[j] * wl[j];
  G2c[((size_t)h * 128 + m) * 128 + d] = f2bf(s * (1.0f / QSCALE));
}

// ---------------- GEMM: C[M,N] = A[M,K] @ B[N,K]^T (+ epilogue) ----------------
// MODE 0: bf16 out, +bias[cc]
// MODE 1: f32 out, +bias[cc]
// MODE 3: block-diag per-head (A col offset nt*128, compact B), NSPLIT-way merge epilogue
//         (o partials are bf16)
// All modes: XCD-chunked bijective block swizzle (m204) for L2 panel locality.
template <int MODE, int NSPLIT>
__global__ __launch_bounds__(256) void gemm_bt(
    const unsigned short* __restrict__ A, const unsigned short* __restrict__ B,
    const float* __restrict__ bias, void* __restrict__ Cout,
    int M, int N, int K, int lda, int ldb,
    const unsigned short* __restrict__ o0buf, const float* __restrict__ zbuf,
    const unsigned short* __restrict__ o1buf, const float* __restrict__ lbuf) {
  __shared__ __align__(16) unsigned short Asm_[128 * 64];
  __shared__ __align__(16) unsigned short Bsm_[128 * 64];
  const int tid = threadIdx.x;
  const int wid = tid >> 6, lane = tid & 63;
  // XCD-chunked bijective swizzle: consecutive swizzled ids share nt (B panel)
  int nwg = gridDim.x * gridDim.y;
  int gid = blockIdx.x + blockIdx.y * gridDim.x;
  int q8 = nwg >> 3, r8 = nwg & 7;
  int xcd = gid & 7, jj = gid >> 3;
  int sw = (xcd < r8 ? xcd * (q8 + 1) : r8 * (q8 + 1) + (xcd - r8) * q8) + jj;
  const int mt = sw % gridDim.x, nt = sw / gridDim.x;
  const int wr = wid >> 1, wc = wid & 1;
  const int acol = (MODE == 3) ? nt * 128 : 0;
  f32x4 acc[4][4] = {};

  const int st_srccol = ((((lane & 7) << 4) ^ ((lane >> 3) << 4)) >> 1);  // elements
  const int st_rowoff = (lane >> 3);

  for (int k0 = 0; k0 < K; k0 += 64) {
    __syncthreads();
#pragma unroll
    for (int r = 0; r < 4; ++r) {
      int c = wid * 4 + r;
      int lrow = c * 8 + st_rowoff;
      int arow = mt * 128 + lrow; if (arow > M - 1) arow = M - 1;
      gload16(A + (size_t)arow * lda + acol + k0 + st_srccol,
              (char*)Asm_ + c * 1024 + lane * 16);
      int brow = nt * 128 + lrow;
      gload16(B + (size_t)brow * ldb + k0 + st_srccol,
              (char*)Bsm_ + c * 1024 + lane * 16);
    }
    __syncthreads();
#pragma unroll
    for (int kk = 0; kk < 2; ++kk) {
      int cb = (kk * 64 + ((lane >> 4) << 4)) ^ ((lane & 7) << 4);
      s16x8 af[4], bfr[4];
#pragma unroll
      for (int m = 0; m < 4; ++m)
        af[m] = *(const s16x8*)((const char*)Asm_ + (wr * 64 + m * 16 + (lane & 15)) * 128 + cb);
#pragma unroll
      for (int n = 0; n < 4; ++n)
        bfr[n] = *(const s16x8*)((const char*)Bsm_ + (wc * 64 + n * 16 + (lane & 15)) * 128 + cb);
#pragma unroll
      for (int m = 0; m < 4; ++m)
#pragma unroll
        for (int n = 0; n < 4; ++n)
          acc[m][n] = __builtin_amdgcn_mfma_f32_16x16x32_bf16(af[m], bfr[n], acc[m][n], 0, 0, 0);
    }
  }
  const int rb = mt * 128 + wr * 64, cbse = nt * 128 + wc * 64;
#pragma unroll
  for (int m = 0; m < 4; ++m) {
#pragma unroll
    for (int n = 0; n < 4; ++n) {
#pragma unroll
      for (int rg = 0; rg < 4; ++rg) {
        int rr = rb + m * 16 + ((lane >> 4) << 2) + rg;
        int cc = cbse + n * 16 + (lane & 15);
        if (rr < M) {
          float v = acc[m][n][rg];
          if (MODE == 0) {
            v += bias[cc];
            ((unsigned short*)Cout)[(size_t)rr * N + cc] = f2bf(v);
          } else if (MODE == 1) {
            v += bias[cc];
            ((float*)Cout)[(size_t)rr * N + cc] = v;
          } else {
            int hd = cc >> 7;
            float lsum = lbuf[(size_t)rr * 12 + hd];
            float osum = bf2f(o0buf[(size_t)rr * N + cc]);
#pragma unroll
            for (int s = 1; s < NSPLIT; ++s) {
              lsum += lbuf[((size_t)s * M + rr) * 12 + hd];
              osum += bf2f(o1buf[(size_t)(s - 1) * M * 1536 + (size_t)rr * N + cc]);
            }
            v = v * zbuf[(size_t)rr * 12 + hd] + osum * (1.0f / lsum) + bias[cc & 127];
            ((unsigned short*)Cout)[(size_t)rr * N + cc] = f2bf(v);
          }
        }
      }
    }
  }
}

// ---------------- fused RMS + RoPE for q (blockIdx.y==0) and k (blockIdx.y==1) -----------
__global__ __launch_bounds__(256) void rms_rope_kernel(
    const unsigned short* __restrict__ qkv, const float* __restrict__ freqs,
    const float* __restrict__ gq, const float* __restrict__ gk,
    const float* __restrict__ g_kmean,
    unsigned short* __restrict__ rqb, unsigned short* __restrict__ rkb,
    float* __restrict__ zbuf, int S,
    const int* __restrict__ hgp, const int* __restrict__ wgp) {
  const int s = blockIdx.x;
  const int isk = blockIdx.y;
  const unsigned short* row = qkv + (size_t)s * 4608 + (isk ? 1536 : 0);
  const float* g = isk ? gk : gq;
  unsigned short* outr = isk ? rkb : rqb;
  float* zout = isk ? nullptr : zbuf;
  const float oscale = isk ? 1.0f : QSCALE;
  const int tid = threadIdx.x;
  const int lane = tid & 63, wid = tid >> 6;
  unsigned int pv0, pv1, pv2;
  float ssq = 0.f;
  {
    pv0 = *(const unsigned int*)(row + 2 * (tid));
    pv1 = *(const unsigned int*)(row + 2 * (tid + 256));
    pv2 = *(const unsigned int*)(row + 2 * (tid + 512));
    float a0 = bf2f((unsigned short)(pv0 & 0xffffu)), b0 = bf2f((unsigned short)(pv0 >> 16));
    float a1 = bf2f((unsigned short)(pv1 & 0xffffu)), b1 = bf2f((unsigned short)(pv1 >> 16));
    float a2 = bf2f((unsigned short)(pv2 & 0xffffu)), b2 = bf2f((unsigned short)(pv2 >> 16));
    ssq = a0 * a0 + b0 * b0 + a1 * a1 + b1 * b1 + a2 * a2 + b2 * b2;
  }
#pragma unroll
  for (int m = 1; m < 64; m <<= 1) ssq += __shfl_xor(ssq, m, 64);
  __shared__ float wpart[4];
  if (lane == 0) wpart[wid] = ssq;
  __syncthreads();
  float tot = wpart[0] + wpart[1] + wpart[2] + wpart[3];
  float rms = rsqrtf(tot * (1.0f / 1536.0f) + 1e-6f);
  const int Wg = *wgp;
  const int HWg = (*hgp) * Wg;
  int fi = s / HWg; int rem = s - fi * HWg;
  int hi = rem / Wg; int wi = rem - hi * Wg;
  unsigned int pvs[3] = {pv0, pv1, pv2};
#pragma unroll
  for (int rd = 0; rd < 3; ++rd) {
    int p = tid + rd * 256;
    int c = p & 63;
    int fidx = (c < 22) ? fi : ((c < 43) ? hi : wi);
    float cr = freqs[fidx * 128 + 2 * c];
    float ci = freqs[fidx * 128 + 2 * c + 1];
    float xr = bf2f((unsigned short)(pvs[rd] & 0xffffu)) * rms * g[2 * p];
    float xi = bf2f((unsigned short)(pvs[rd] >> 16)) * rms * g[2 * p + 1];
    float yr = (xr * cr - xi * ci) * oscale;
    float yi = (xr * ci + xi * cr) * oscale;
    unsigned int ow = (unsigned int)f2bf(yr) | ((unsigned int)f2bf(yi) << 16);
    *(unsigned int*)(outr + (size_t)s * 1536 + 2 * p) = ow;
    if (zout != nullptr) {
      int head = p >> 6;
      float part = fmaxf(xr, 0.f) * g_kmean[head * 128 + 2 * c] +
                   fmaxf(xi, 0.f) * g_kmean[head * 128 + 2 * c + 1];
#pragma unroll
      for (int m = 1; m < 64; m <<= 1) part += __shfl_xor(part, m, 64);
      if (lane == 0) zout[(size_t)s * 12 + head] = 1.0f / (part + 1e-6f);
    }
  }
}

// ---------------- V transpose: vpre (S, ld cols used 64) bf16 -> vt (1536, S) bf16 ----------------
__global__ __launch_bounds__(256) void vtrans_kernel(const unsigned short* __restrict__ vpre,
                                                     unsigned short* __restrict__ vt, int S, int ld) {
  __shared__ unsigned short tile[64][66];
  int t0 = blockIdx.x * 64, c0 = blockIdx.y * 64;
  int tid = threadIdx.x;
#pragma unroll
  for (int rep = 0; rep < 16; ++rep) {
    int lin = rep * 256 + tid;
    int i = lin >> 6, j = lin & 63;
    int t = t0 + i; if (t > S - 1) t = S - 1;
    tile[i][j] = vpre[(size_t)t * ld + c0 + j];
  }
  __syncthreads();
#pragma unroll
  for (int rep = 0; rep < 16; ++rep) {
    int lin = rep * 256 + tid;
    int j = lin >> 6, i = lin & 63;
    int t = t0 + i;
    if (t < S) vt[(size_t)(c0 + j) * S + t] = tile[i][j];
  }
}

// ---------------- Flash attention, 32x32 MFMA, in-register P (permlane32_swap), ----------
// ---------------- no-max softmax, KV-split x nsplit, conflict-free LDS -------------------
// R16 structure; ONLY change: o partials written as bf16 (halves partial traffic).
__global__ __launch_bounds__(256, 3) void attn_kernel(
    const unsigned short* __restrict__ rq, const unsigned short* __restrict__ rk,
    const unsigned short* __restrict__ vt, unsigned short* __restrict__ o0buf,
    unsigned short* __restrict__ o1buf, float* __restrict__ lbuf, int S, int nqb, int nsplit) {
  __shared__ __align__(16) unsigned short Ks[2][32 * 128];  // [tok][256B], key (tok&15)<<4
  __shared__ __align__(16) unsigned short Vs[2][32 * 128];  // [d&31][256B: (d>>5)*64+2*tok], key (row&15)<<4
  const int tid = threadIdx.x, wid = tid >> 6, lane = tid & 63;
  const int q32 = lane & 31, hi = lane >> 5;

  const int total = nqb * 12 * nsplit;
  int lg = blockIdx.x;
  if ((total & 7) == 0) lg = (lg & 7) * (total >> 3) + (lg >> 3);
  const int z = lg / (nqb * 12);
  int rem = lg - z * nqb * 12;
  const int h = rem / nqb;
  const int qb = rem - h * nqb;
  const int q0 = qb * 128 + wid * 32;

  const int seg = (((S + nsplit - 1) / nsplit) + 31) & ~31;
  const int tbeg = z * seg;
  const int tend = (tbeg + seg < S) ? (tbeg + seg) : S;
  unsigned short* obufz = (z == 0) ? o0buf : (o1buf + (size_t)(z - 1) * S * 1536);
  float* lbufz = lbuf + (size_t)z * S * 12;

  s16x8 qf[8];
  {
    int qrow = q0 + q32; if (qrow > S - 1) qrow = S - 1;
    const unsigned short* qp = rq + (size_t)qrow * 1536 + h * 128 + hi * 8;
#pragma unroll
    for (int dblk = 0; dblk < 8; ++dblk) qf[dblk] = *(const s16x8*)(qp + dblk * 16);
  }
  f32x16 o0 = {}, o1 = {}, o2 = {}, o3 = {};
  float lsum = 0.f;

  const int st_row0 = tid >> 4;           // + 16*r
  const int st_off = (tid & 15) * 16;     // byte offset within 256B row (dest)
  const int kswz = (q32 & 15) << 4;       // read-side K key
  const int vswz = (q32 & 15) << 4;       // read-side V key

#define STAGE(buf, t0s)                                                            \
  {                                                                                \
    _Pragma("unroll") for (int r = 0; r < 2; ++r) {                                \
      int row = st_row0 + 16 * r;                                                  \
      int key = (row & 15) << 4;                                                   \
      int kL = st_off ^ key;                                                       \
      int trow = (t0s) + row; if (trow > S - 1) trow = S - 1;                      \
      gload16(rk + (size_t)trow * 1536 + h * 128 + (kL >> 1),                      \
              (char*)Ks[buf] + r * 4096 + tid * 16);                               \
      int vL = st_off ^ key;                                                       \
      int vd = row + 32 * (vL >> 6);                                               \
      int vtok = (t0s) + ((vL & 63) >> 1); if (vtok > S - 8) vtok = S - 8;         \
      gload16(vt + (size_t)(h * 128 + vd) * S + vtok,                              \
              (char*)Vs[buf] + r * 4096 + tid * 16);                               \
    }                                                                              \
  }

  STAGE(0, tbeg);
  __syncthreads();
  int cur = 0;
  for (int t0 = tbeg; t0 < tend; t0 += 32) {
    if (t0 + 32 < tend) STAGE(cur ^ 1, t0 + 32);
    f32x16 sc = {};
    __builtin_amdgcn_s_setprio(1);
#pragma unroll
    for (int dblk = 0; dblk < 8; ++dblk) {
      s16x8 kfr = *(const s16x8*)((const char*)Ks[cur] + q32 * 256 +
                                  ((dblk * 32 + hi * 16) ^ kswz));
      sc = __builtin_amdgcn_mfma_f32_32x32x16_bf16(kfr, qf[dblk], sc, 0, 0, 0);
    }
    __builtin_amdgcn_s_setprio(0);
    const bool full = (t0 + 32 <= tend);
    unsigned int pk[8];
    float rs = 0.f;
#pragma unroll
    for (int j = 0; j < 8; ++j) {
      float p0, p1;
      if (full) {
        p0 = fast_exp2(sc[2 * j]);
        p1 = fast_exp2(sc[2 * j + 1]);
      } else {
        int r0 = 2 * j;
        int tk0 = t0 + (r0 & 3) + 8 * (r0 >> 2) + 4 * hi;
        p0 = (tk0 < tend) ? fast_exp2(sc[2 * j]) : 0.f;
        p1 = (tk0 + 1 < tend) ? fast_exp2(sc[2 * j + 1]) : 0.f;
      }
      unsigned int u0 = __float_as_uint(p0) & 0xffff0000u;
      unsigned int u1 = __float_as_uint(p1) & 0xffff0000u;
      rs += __uint_as_float(u0) + __uint_as_float(u1);
      pk[j] = (u0 >> 16) | u1;
    }
    lsum += rs;
    unsigned int x0 = pk[0], y0 = pk[2], x1 = pk[1], y1 = pk[3];
    asm("v_permlane32_swap_b32 %0, %1" : "+v"(x0), "+v"(y0));
    asm("v_permlane32_swap_b32 %0, %1" : "+v"(x1), "+v"(y1));
    unsigned int x2 = pk[4], y2 = pk[6], x3 = pk[5], y3 = pk[7];
    asm("v_permlane32_swap_b32 %0, %1" : "+v"(x2), "+v"(y2));
    asm("v_permlane32_swap_b32 %0, %1" : "+v"(x3), "+v"(y3));
    u32x4 pa0v = {x0, x1, y0, y1};
    u32x4 pa1v = {x2, x3, y2, y3};
    s16x8 pa0 = __builtin_bit_cast(s16x8, pa0v);
    s16x8 pa1 = __builtin_bit_cast(s16x8, pa1v);
    __builtin_amdgcn_s_setprio(1);
    {
      const char* vrowb = (const char*)Vs[cur] + q32 * 256;
#pragma unroll
      for (int ks = 0; ks < 2; ++ks) {
        s16x8 pa = ks ? pa1 : pa0;
        s16x8 vb;
        vb = *(const s16x8*)(vrowb + ((0 * 64 + ks * 32 + hi * 16) ^ vswz));
        o0 = __builtin_amdgcn_mfma_f32_32x32x16_bf16(pa, vb, o0, 0, 0, 0);
        vb = *(const s16x8*)(vrowb + ((1 * 64 + ks * 32 + hi * 16) ^ vswz));
        o1 = __builtin_amdgcn_mfma_f32_32x32x16_bf16(pa, vb, o1, 0, 0, 0);
        vb = *(const s16x8*)(vrowb + ((2 * 64 + ks * 32 + hi * 16) ^ vswz));
        o2 = __builtin_amdgcn_mfma_f32_32x32x16_bf16(pa, vb, o2, 0, 0, 0);
        vb = *(const s16x8*)(vrowb + ((3 * 64 + ks * 32 + hi * 16) ^ vswz));
        o3 = __builtin_amdgcn_mfma_f32_32x32x16_bf16(pa, vb, o3, 0, 0, 0);
      }
    }
    __builtin_amdgcn_s_setprio(0);
    __syncthreads();
    cur ^= 1;
  }
  lsum += __shfl_xor(lsum, 32, 64);
  {
    int qrow = q0 + q32;
    if (hi == 0 && qrow < S) lbufz[(size_t)qrow * 12 + h] = lsum;
  }
#pragma unroll
  for (int r = 0; r < 16; ++r) {
    int qrow = q0 + (r & 3) + 8 * (r >> 2) + 4 * hi;
    if (qrow < S) {
      unsigned short* orow = obufz + (size_t)qrow * 1536 + h * 128 + q32;
      orow[0] = f2bf(o0[r]); orow[32] = f2bf(o1[r]);
      orow[64] = f2bf(o2[r]); orow[96] = f2bf(o3[r]);
    }
  }
#undef STAGE
}

extern "C" void kernel_launch(void* const* d_in, const int* in_sizes, int n_in,
                              void* d_out, int out_size, void* d_ws, size_t ws_size,
                              hipStream_t stream) {
  const float* x = (const float*)d_in[0];
  const float* freqs = (const float*)d_in[1];
  const float* g_kmean = (const float*)d_in[2];
  const float* g_kv = (const float*)d_in[3];
  const float* Wq = (const float*)d_in[4];  const float* bq = (const float*)d_in[5];
  const float* Wk = (const float*)d_in[6];  const float* bk = (const float*)d_in[7];
  const float* Wv = (const float*)d_in[8];  const float* bv = (const float*)d_in[9];
  const float* Wo = (const float*)d_in[10]; const float* bo = (const float*)d_in[11];
  const float* gq = (const float*)d_in[12]; const float* gk = (const float*)d_in[13];
  const float* Wlin = (const float*)d_in[14]; const float* blin = (const float*)d_in[15];
  const int* hgp = (const int*)d_in[17];
  const int* wgp = (const int*)d_in[18];

  const int S = in_sizes[0] / 1536;

  char* ws = (char*)d_ws;
  const size_t SZ = (size_t)S * 1536 * 2;        // bf16 (S,1536)
  const size_t WSZ = (size_t)1536 * 1536 * 2;    // bf16 1536^2
  const size_t QKVSZ = (size_t)S * 4608 * 2;     // bf16 (S,4608)
  const size_t G2SZ = (size_t)12 * 128 * 128 * 2;
  size_t o_xbf = 0;
  size_t o_wqkv = o_xbf + SZ;
  size_t o_wo = o_wqkv + 3 * WSZ;                // contiguous after wqkv
  size_t o_g2 = o_wo + WSZ;
  size_t o_qkv = o_g2 + G2SZ;                    // later: o-partial 0 (bf16, SZ) + ybf (SZ)
  size_t o_rk = o_qkv + QKVSZ;
  size_t o_vt = o_rk + SZ;
  size_t o_z = o_vt + SZ;
  size_t o_bqkv = o_z + (size_t)S * 12 * 4;
  size_t o_o1 = o_bqkv + 4608 * 4;               // extra bf16 o-partials (nsplit-1)

  int nsplit = 3;
  if (ws_size < o_o1 + (size_t)2 * SZ + (size_t)3 * S * 12 * 4) nsplit = 2;
  size_t o_l = o_o1 + (size_t)(nsplit - 1) * SZ;
  size_t need = o_l + (size_t)nsplit * S * 12 * 4;
  if (ws_size < need) return;

  unsigned short* xbf = (unsigned short*)(ws + o_xbf);
  unsigned short* wqkv = (unsigned short*)(ws + o_wqkv);
  unsigned short* wob = (unsigned short*)(ws + o_wo);
  unsigned short* g2c = (unsigned short*)(ws + o_g2);
  unsigned short* qkv = (unsigned short*)(ws + o_qkv);
  unsigned short* rkb = (unsigned short*)(ws + o_rk);
  unsigned short* vtb = (unsigned short*)(ws + o_vt);
  float* zbuf = (float*)(ws + o_z);
  float* bqkv = (float*)(ws + o_bqkv);
  unsigned short* rqb = xbf;
  unsigned short* o0buf = (unsigned short*)(ws + o_qkv);     // aliases qkv (dead after rope/vtrans)
  unsigned short* o1buf = (unsigned short*)(ws + o_o1);
  float* lbuf = (float*)(ws + o_l);
  unsigned short* ybf = (unsigned short*)(ws + o_qkv + SZ);  // after o-partial 0

  // 1) casts
  {
    int n4 = (S * 1536) / 4;
    cast_f32_bf16_x4<<<(n4 + 255) / 256, 256, 0, stream>>>(x, xbf, n4);
    int per4 = (1536 * 1536) / 4;
    cast_weights4<<<(4 * per4 + 255) / 256, 256, 0, stream>>>(Wq, Wk, Wv, Wo, wqkv, per4);
  }
  hipMemcpyAsync(bqkv, bq, 1536 * 4, hipMemcpyDeviceToDevice, stream);
  hipMemcpyAsync(bqkv + 1536, bk, 1536 * 4, hipMemcpyDeviceToDevice, stream);
  hipMemcpyAsync(bqkv + 3072, bv, 1536 * 4, hipMemcpyDeviceToDevice, stream);

  // 2) compact block-diagonal G2c
  g2fill_kernel<<<dim3(12, 128), 128, 0, stream>>>(g_kv, Wlin, g2c);

  // 3) merged QKV projection (128^2 GEMM + XCD swizzle): qkv[S][4608]
  {
    dim3 ggrid((S + 127) / 128, 36);
    gemm_bt<0, 2><<<ggrid, 256, 0, stream>>>(xbf, wqkv, bqkv, qkv, S, 4608, 1536, 1536, 1536,
                                             nullptr, nullptr, nullptr, nullptr);
  }

  // 4) fused RMS + RoPE for q and k (+z for q)
  rms_rope_kernel<<<dim3(S, 2), 256, 0, stream>>>(qkv, freqs, gq, gk, g_kmean,
                                                  rqb, rkb, zbuf, S, hgp, wgp);

  // 5) V transpose
  vtrans_kernel<<<dim3((S + 63) / 64, 24), 256, 0, stream>>>(qkv + 3072, vtb, S, 4608);

  // 6) attention, KV-split x nsplit (bf16 o-partials)
  {
    int nqb = (S + 127) / 128;
    attn_kernel<<<dim3(nqb * 12 * nsplit), 256, 0, stream>>>(rqb, rkb, vtb,
                                                             o0buf, o1buf, lbuf, S, nqb, nsplit);
  }

  // 7) xg merge (block-diag, K=128) -> ybf ; 8) out GEMM
  {
    dim3 ggrid((S + 127) / 128, 12);
    if (nsplit == 3) {
      gemm_bt<3, 3><<<ggrid, 256, 0, stream>>>(rqb, g2c, blin, ybf, S, 1536, 128, 1536, 128,
                                               o0buf, zbuf, o1buf, lbuf);
    } else {
      gemm_bt<3, 2><<<ggrid, 256, 0, stream>>>(rqb, g2c, blin, ybf, S, 1536, 128, 1536, 128,
                                               o0buf, zbuf, o1buf, lbuf);
    }
    gemm_bt<1, 2><<<ggrid, 256, 0, stream>>>(ybf, wob, bo, (float*)d_out, S, 1536, 1536, 1536, 1536,
                                             nullptr, nullptr, nullptr, nullptr);
  }
}